// Round 4
// baseline (1233.998 us; speedup 1.0000x reference)
//
#include <hip/hip_runtime.h>
#include <hip/hip_bf16.h>
#include <cstdint>
#include <cstddef>

#define T_LEN 4096
#define TP 4104      // padded t rows: pixel t lives at row t+2; rows 0,1 and 4098..4103 are zero
#define BATCH 32
#define NMELS 80
#define HID 128
#define W_WORDS 64
#define D_MAX 100
#define WHALO 68
#define DHALO 120    // pixel d at halo row d+2; rows 0,1 and 102..119 zero

typedef __attribute__((ext_vector_type(4))) float f32x4;
typedef __attribute__((ext_vector_type(8))) short short8;

static __device__ __forceinline__ unsigned short f2bf(float f) {
    __hip_bfloat16 h = __float2bfloat16(f);
    return *reinterpret_cast<unsigned short*>(&h);
}

// ---------- pack weights into MFMA A-fragment order ----------
// wf[((cc*TAPS + tap)*8 + mi)*512 + lane*8 + j] = w[co][ci][tap], co=mi*16+(lane&15), ci=cc*32+(lane>>4)*8+j
template <int CIN, int CC, int TAPS>
__global__ __launch_bounds__(256) void pack_w_kernel(const float* __restrict__ w,
                                                     __hip_bfloat16* __restrict__ wf) {
    int idx = blockIdx.x * 256 + threadIdx.x; // CC*TAPS*8*64*8
    int r = idx;
    int j = r & 7; r >>= 3;
    int lane = r & 63; r >>= 6;
    int mi = r & 7; r >>= 3;
    int tap = r % TAPS;
    int cc = r / TAPS;
    if (cc >= CC) return;
    int co = mi * 16 + (lane & 15);
    int ci = cc * 32 + (lane >> 4) * 8 + j;
    float v = (ci < CIN) ? w[(co * CIN + ci) * TAPS + tap] : 0.f;
    wf[idx] = __float2bfloat16(v);
}

// ---------- cast features (b,80,t) fp32 -> XF (b,TP,96) bf16, interior rows ----------
__global__ __launch_bounds__(256) void cast_feat_kernel(const float* __restrict__ f,
                                                        __hip_bfloat16* __restrict__ xf) {
    int idx = blockIdx.x * 256 + threadIdx.x; // 32*4096*96
    int c = idx % 96;
    int r = idx / 96;
    int t = r & 4095;
    int b = r >> 12;
    float v = (c < NMELS) ? f[((size_t)b * NMELS + c) * T_LEN + t] : 0.f;
    xf[((size_t)b * TP + t + 2) * 96 + c] = __float2bfloat16(v);
}

// ---------- unified MFMA conv kernel (co-split: each wave does 64 co = 4 m-tiles) ----------
// out[pixel][co] = act( sum_{tap,ci} W[co][ci][tap] * In[pixel_shift(tap)][ci] + bias[co] )
// blockIdx.x LSB = co-half (so act-sharing blocks are dispatch-adjacent); rest = pixel tile.
// OMODE: 0 = 1D (rows TP, out stride 128, +2 halo), 1 = 2D->halo plane, 2 = 2D->compact (b,64,100,128)
template <int IC, int CC, int TH, int TW, int PRS, int NT, bool RELU, bool DMASK, int OMODE, int D0>
__global__ __launch_bounds__(256, 4) void convmfma_kernel(const __hip_bfloat16* __restrict__ in,
                                                          const __hip_bfloat16* __restrict__ wf,
                                                          const float* __restrict__ bias,
                                                          __hip_bfloat16* __restrict__ outp) {
    const int tid = threadIdx.x;
    const int lane = tid & 63;
    const int wid = tid >> 6;
    const int cohalf = blockIdx.x & 1;
    const int bx = blockIdx.x >> 1;
    const int b = blockIdx.y;

    int in_base, out_base;
    if (OMODE == 0) {
        const int pix0 = bx * 256 + wid * 64;
        in_base = (b * TP + pix0) * IC;
        out_base = (b * TP + pix0 + 2) * 128;
    } else {
        const int w = bx * 4 + wid;
        in_base = ((b * WHALO + w) * DHALO + D0) * IC;
        if (OMODE == 1)
            out_base = ((b * WHALO + w + 2) * DHALO + D0 + 2) * 128;
        else
            out_base = ((b * 64 + w) * 100 + D0) * 128;
    }

    f32x4 acc[NT][4];
#pragma unroll
    for (int n = 0; n < NT; n++)
#pragma unroll
        for (int mi = 0; mi < 4; mi++) acc[n][mi] = (f32x4)0.f;

    const short* inp = (const short*)in;
    const short* wfp = (const short*)wf;

#pragma unroll 1
    for (int cc = 0; cc < CC; cc++) {
#pragma unroll 1
        for (int th = 0; th < TH; th++) {
#pragma unroll
            for (int tw = 0; tw < TW; tw++) {
                const int tap = th * TW + tw;
                const short* wptr =
                    wfp + ((cc * (TH * TW) + tap) * 8 + cohalf * 4) * 512 + lane * 8;
                short8 wfr[4];
#pragma unroll
                for (int mi = 0; mi < 4; mi++) wfr[mi] = *(const short8*)(wptr + mi * 512);

                const short* xptr = inp + in_base + (th * PRS + tw) * IC + (lane & 15) * IC +
                                    (lane >> 4) * 8 + cc * 32;
                short8 xfr[NT];
#pragma unroll
                for (int n = 0; n < NT; n++) xfr[n] = *(const short8*)(xptr + n * 16 * IC);

#pragma unroll
                for (int n = 0; n < NT; n++)
#pragma unroll
                    for (int mi = 0; mi < 4; mi++)
                        acc[n][mi] = __builtin_amdgcn_mfma_f32_16x16x32_bf16(wfr[mi], xfr[n],
                                                                             acc[n][mi], 0, 0, 0);
            }
        }
    }

    unsigned short* outp16 = (unsigned short*)outp;
#pragma unroll
    for (int mi = 0; mi < 4; mi++) {
        const float4 bv = *(const float4*)(bias + cohalf * 64 + mi * 16 + (lane >> 4) * 4);
#pragma unroll
        for (int n = 0; n < NT; n++) {
            const int pix = n * 16 + (lane & 15);
            if (DMASK && (D0 + pix >= 100)) continue;
            f32x4 v = acc[n][mi];
            float v0 = v[0] + bv.x, v1 = v[1] + bv.y, v2 = v[2] + bv.z, v3 = v[3] + bv.w;
            if (RELU) {
                v0 = fmaxf(v0, 0.f); v1 = fmaxf(v1, 0.f);
                v2 = fmaxf(v2, 0.f); v3 = fmaxf(v3, 0.f);
            }
            ushort4 o;
            o.x = f2bf(v0); o.y = f2bf(v1); o.z = f2bf(v2); o.w = f2bf(v3);
            *(ushort4*)(outp16 + out_base + pix * 128 + cohalf * 64 + mi * 16 +
                        (lane >> 4) * 4) = o;
        }
    }
}

// ---------- gather: E (b,TP,128) bf16 -> P4 (b,WHALO,DHALO,128) bf16 interior ----------
__global__ __launch_bounds__(256) void gather_kernel(const __hip_bfloat16* __restrict__ E,
                                                     const int* __restrict__ wb,
                                                     __hip_bfloat16* __restrict__ P) {
    const int w = blockIdx.x;
    const int b = blockIdx.y;
    const int start = wb[(b * W_WORDS + w) * 2 + 0];
    const int end = wb[(b * W_WORDS + w) * 2 + 1];
    const int dur = end - start;
    const int base_e = (b * TP + start + 2) * 128;
    const int base_p = ((b * WHALO + w + 2) * DHALO + 2) * 128;
    const unsigned short* ep = (const unsigned short*)E;
    unsigned short* pp = (unsigned short*)P;
    for (int i = threadIdx.x; i < D_MAX * 64; i += 256) {
        int c2 = (i & 63) * 2;
        int d = i >> 6;
        unsigned int v = (d < dur) ? *(const unsigned int*)(ep + base_e + d * 128 + c2) : 0u;
        *(unsigned int*)(pp + base_p + d * 128 + c2) = v;
    }
}

// ---------- einsum over d + relu: Q (b,64,100,128) bf16 -> xe (b,128,64) fp32 ----------
__global__ __launch_bounds__(128) void einsum_kernel(const __hip_bfloat16* __restrict__ Q,
                                                     const float* __restrict__ lw,
                                                     const float* __restrict__ lb,
                                                     float* __restrict__ xe) {
    const int w = blockIdx.x;
    const int b = blockIdx.y;
    const int c = threadIdx.x;
    const unsigned short* qp = (const unsigned short*)Q + ((b * 64 + w) * 100) * 128 + c;
    float acc = 0.f;
#pragma unroll 4
    for (int d = 0; d < D_MAX; d++) {
        unsigned int u = (unsigned int)qp[d * 128] << 16;
        acc += *reinterpret_cast<float*>(&u) * lw[d];
    }
    xe[(b * 128 + c) * 64 + w] = fmaxf(acc + lb[0], 0.f);
}

// ---------- final conv: xe (b,128,64) fp32 -> out (b,64); only kw==2 column of w6 ----------
__global__ void conv6_kernel(const float* __restrict__ xe, const float* __restrict__ w6,
                             const float* __restrict__ b6, float* __restrict__ out) {
    int b = blockIdx.x;
    int w = threadIdx.x; // 64
    float acc = b6[0];
#pragma unroll 1
    for (int ci = 0; ci < 128; ci++) {
        const float* xr = xe + (b * 128 + ci) * 64;
#pragma unroll
        for (int kh = 0; kh < 5; kh++) {
            int ww = w + kh - 2;
            if ((unsigned)ww < 64u) acc += xr[ww] * w6[ci * 25 + kh * 5 + 2];
        }
    }
    out[b * 64 + w] = acc;
}

extern "C" void kernel_launch(void* const* d_in, const int* in_sizes, int n_in,
                              void* d_out, int out_size, void* d_ws, size_t ws_size,
                              hipStream_t stream) {
    const float* features = (const float*)d_in[0];
    const int* wbnd = (const int*)d_in[1];
    const float* w1 = (const float*)d_in[2];
    const float* b1 = (const float*)d_in[3];
    const float* w2 = (const float*)d_in[4];
    const float* b2 = (const float*)d_in[5];
    const float* w3 = (const float*)d_in[6];
    const float* b3 = (const float*)d_in[7];
    const float* w4 = (const float*)d_in[8];
    const float* b4 = (const float*)d_in[9];
    const float* w5 = (const float*)d_in[10];
    const float* b5 = (const float*)d_in[11];
    const float* lw = (const float*)d_in[12];
    const float* lb = (const float*)d_in[13];
    const float* w6 = (const float*)d_in[14];
    const float* b6 = (const float*)d_in[15];
    float* out = (float*)d_out;

    char* base = (char*)d_ws;
    size_t off = 0;
    auto alloc = [&](size_t bytes) -> char* {
        char* p = base + off;
        off += (bytes + 255) & ~(size_t)255;
        return p;
    };

    __hip_bfloat16* XF = (__hip_bfloat16*)alloc((size_t)BATCH * TP * 96 * 2);
    __hip_bfloat16* Y1 = (__hip_bfloat16*)alloc((size_t)BATCH * TP * 128 * 2);
    __hip_bfloat16* Y2 = (__hip_bfloat16*)alloc((size_t)BATCH * TP * 128 * 2);
    __hip_bfloat16* P4 = (__hip_bfloat16*)alloc((size_t)BATCH * WHALO * DHALO * 128 * 2);
    __hip_bfloat16* P5 = (__hip_bfloat16*)alloc((size_t)BATCH * WHALO * DHALO * 128 * 2);
    float* XE = (float*)alloc((size_t)BATCH * 128 * 64 * 4);
    __hip_bfloat16* WF1 = (__hip_bfloat16*)alloc((size_t)3 * 5 * 8 * 512 * 2);
    __hip_bfloat16* WF2 = (__hip_bfloat16*)alloc((size_t)4 * 5 * 8 * 512 * 2);
    __hip_bfloat16* WF3 = (__hip_bfloat16*)alloc((size_t)4 * 5 * 8 * 512 * 2);
    __hip_bfloat16* WF4 = (__hip_bfloat16*)alloc((size_t)4 * 25 * 8 * 512 * 2);
    __hip_bfloat16* WF5 = (__hip_bfloat16*)alloc((size_t)4 * 25 * 8 * 512 * 2);
    __hip_bfloat16* Q = P4; // conv5 output reuses P4 (dead after conv4)

    // zero halos (and padding channels) — interiors are fully overwritten each call
    hipMemsetAsync(XF, 0, (size_t)BATCH * TP * 96 * 2, stream);
    hipMemsetAsync(Y1, 0, (size_t)BATCH * TP * 128 * 2, stream);
    hipMemsetAsync(Y2, 0, (size_t)BATCH * TP * 128 * 2, stream);
    hipMemsetAsync(P4, 0, (size_t)BATCH * WHALO * DHALO * 128 * 2, stream);
    hipMemsetAsync(P5, 0, (size_t)BATCH * WHALO * DHALO * 128 * 2, stream);

    pack_w_kernel<80, 3, 5><<<240, 256, 0, stream>>>(w1, WF1);
    pack_w_kernel<128, 4, 5><<<320, 256, 0, stream>>>(w2, WF2);
    pack_w_kernel<128, 4, 5><<<320, 256, 0, stream>>>(w3, WF3);
    pack_w_kernel<128, 4, 25><<<1600, 256, 0, stream>>>(w4, WF4);
    pack_w_kernel<128, 4, 25><<<1600, 256, 0, stream>>>(w5, WF5);

    cast_feat_kernel<<<49152, 256, 0, stream>>>(features, XF);

    // conv1d stack (1D: TH=5, TW=1, PRS=1, NT=4 -> 64 pixels/wave; grid x = tile*2 + cohalf)
    convmfma_kernel<96, 3, 5, 1, 1, 4, true, false, 0, 0>
        <<<dim3(32, 32), 256, 0, stream>>>(XF, WF1, b1, Y1);
    convmfma_kernel<128, 4, 5, 1, 1, 4, true, false, 0, 0>
        <<<dim3(32, 32), 256, 0, stream>>>(Y1, WF2, b2, Y2);
    convmfma_kernel<128, 4, 5, 1, 1, 4, false, false, 0, 0>
        <<<dim3(32, 32), 256, 0, stream>>>(Y2, WF3, b3, Y1); // E := Y1

    gather_kernel<<<dim3(64, 32), 256, 0, stream>>>(Y1, wbnd, P4);

    // conv4: P4 -> P5 (halo layout). main d 0..63, tail d 64..99 (masked)
    convmfma_kernel<128, 4, 5, 5, DHALO, 4, true, false, 1, 0>
        <<<dim3(32, 32), 256, 0, stream>>>(P4, WF4, b4, P5);
    convmfma_kernel<128, 4, 5, 5, DHALO, 3, true, true, 1, 64>
        <<<dim3(32, 32), 256, 0, stream>>>(P4, WF4, b4, P5);

    // conv5: P5 -> Q (compact b,64,100,128)
    convmfma_kernel<128, 4, 5, 5, DHALO, 4, true, false, 2, 0>
        <<<dim3(32, 32), 256, 0, stream>>>(P5, WF5, b5, Q);
    convmfma_kernel<128, 4, 5, 5, DHALO, 3, true, true, 2, 64>
        <<<dim3(32, 32), 256, 0, stream>>>(P5, WF5, b5, Q);

    einsum_kernel<<<dim3(64, 32), 128, 0, stream>>>(Q, lw, lb, XE);
    conv6_kernel<<<32, 64, 0, stream>>>(XE, w6, b6, out);
}

// Round 6
// 898.926 us; speedup vs baseline: 1.3727x; 1.3727x over previous
//
#include <hip/hip_runtime.h>
#include <hip/hip_bf16.h>
#include <cstdint>
#include <cstddef>

#define T_LEN 4096
#define TP 4104      // padded t rows: pixel t lives at row t+2; rows 0,1 and 4098..4103 are zero
#define BATCH 32
#define NMELS 80
#define HID 128
#define W_WORDS 64
#define D_MAX 100
#define WHALO 68
#define DHALO 120    // pixel d at halo row d+2; rows 0,1 and 102..119 zero

typedef __attribute__((ext_vector_type(4))) float f32x4;
typedef __attribute__((ext_vector_type(8))) short short8;

static __device__ __forceinline__ unsigned short f2bf(float f) {
    __hip_bfloat16 h = __float2bfloat16(f);
    return *reinterpret_cast<unsigned short*>(&h);
}

// ---------- pack weights into MFMA A-fragment order ----------
// wf[((cc*TAPS + tap)*8 + mi)*512 + lane*8 + j] = w[co][ci][tap], co=mi*16+(lane&15), ci=cc*32+(lane>>4)*8+j
template <int CIN, int CC, int TAPS>
__global__ __launch_bounds__(256) void pack_w_kernel(const float* __restrict__ w,
                                                     __hip_bfloat16* __restrict__ wf) {
    int idx = blockIdx.x * 256 + threadIdx.x; // CC*TAPS*8*64*8
    int r = idx;
    int j = r & 7; r >>= 3;
    int lane = r & 63; r >>= 6;
    int mi = r & 7; r >>= 3;
    int tap = r % TAPS;
    int cc = r / TAPS;
    if (cc >= CC) return;
    int co = mi * 16 + (lane & 15);
    int ci = cc * 32 + (lane >> 4) * 8 + j;
    float v = (ci < CIN) ? w[(co * CIN + ci) * TAPS + tap] : 0.f;
    wf[idx] = __float2bfloat16(v);
}

// ---------- cast features (b,80,t) fp32 -> XF (b,TP,96) bf16, interior rows ----------
__global__ __launch_bounds__(256) void cast_feat_kernel(const float* __restrict__ f,
                                                        __hip_bfloat16* __restrict__ xf) {
    int idx = blockIdx.x * 256 + threadIdx.x; // 32*4096*96
    int c = idx % 96;
    int r = idx / 96;
    int t = r & 4095;
    int b = r >> 12;
    float v = (c < NMELS) ? f[((size_t)b * NMELS + c) * T_LEN + t] : 0.f;
    xf[((size_t)b * TP + t + 2) * 96 + c] = __float2bfloat16(v);
}

// ---------- conv1d MFMA kernel (round-3 form: wave = 64 px, all 128 co) ----------
template <int IC, int CC, bool RELU>
__global__ __launch_bounds__(256) void conv1d_mfma_kernel(const __hip_bfloat16* __restrict__ in,
                                                          const __hip_bfloat16* __restrict__ wf,
                                                          const float* __restrict__ bias,
                                                          __hip_bfloat16* __restrict__ outp) {
    const int tid = threadIdx.x;
    const int lane = tid & 63;
    const int wid = tid >> 6;
    const int pix0 = blockIdx.x * 256 + wid * 64;
    const int b = blockIdx.y;

    const int in_base = (b * TP + pix0) * IC;
    const int out_base = (b * TP + pix0 + 2) * 128;

    f32x4 acc[4][8];
#pragma unroll
    for (int n = 0; n < 4; n++)
#pragma unroll
        for (int mi = 0; mi < 8; mi++) acc[n][mi] = (f32x4)0.f;

    const short* inp = (const short*)in;
    const short* wfp = (const short*)wf;

#pragma unroll 1
    for (int cc = 0; cc < CC; cc++) {
#pragma unroll 1
        for (int th = 0; th < 5; th++) {
            const short* wptr = wfp + ((cc * 5 + th) * 8) * 512 + lane * 8;
            short8 wfr[8];
#pragma unroll
            for (int mi = 0; mi < 8; mi++) wfr[mi] = *(const short8*)(wptr + mi * 512);

            const short* xptr =
                inp + in_base + th * IC + (lane & 15) * IC + (lane >> 4) * 8 + cc * 32;
            short8 xfr[4];
#pragma unroll
            for (int n = 0; n < 4; n++) xfr[n] = *(const short8*)(xptr + n * 16 * IC);

#pragma unroll
            for (int n = 0; n < 4; n++)
#pragma unroll
                for (int mi = 0; mi < 8; mi++)
                    acc[n][mi] =
                        __builtin_amdgcn_mfma_f32_16x16x32_bf16(wfr[mi], xfr[n], acc[n][mi], 0, 0, 0);
        }
    }

    unsigned short* outp16 = (unsigned short*)outp;
#pragma unroll
    for (int mi = 0; mi < 8; mi++) {
        const float4 bv = *(const float4*)(bias + mi * 16 + (lane >> 4) * 4);
#pragma unroll
        for (int n = 0; n < 4; n++) {
            const int pix = n * 16 + (lane & 15);
            f32x4 v = acc[n][mi];
            float v0 = v[0] + bv.x, v1 = v[1] + bv.y, v2 = v[2] + bv.z, v3 = v[3] + bv.w;
            if (RELU) {
                v0 = fmaxf(v0, 0.f); v1 = fmaxf(v1, 0.f);
                v2 = fmaxf(v2, 0.f); v3 = fmaxf(v3, 0.f);
            }
            ushort4 o;
            o.x = f2bf(v0); o.y = f2bf(v1); o.z = f2bf(v2); o.w = f2bf(v3);
            *(ushort4*)(outp16 + out_base + pix * 128 + mi * 16 + (lane >> 4) * 4) = o;
        }
    }
}

// ---------- conv2d MFMA with LDS-staged activations ----------
// Block = 4 waves = 4 adjacent w rows; stages [8 rows][NC cols][32 ci] per cc slice.
// LDS padded to 36 shorts per (row,col) cell: 8B-aligned, near-conflict-free.
// OMODE: 1 = out to halo plane, 2 = out to compact (b,64,100,128)
template <int NT, bool RELU, bool DMASK, int OMODE, int D0>
__global__ __launch_bounds__(256) void conv2d_lds_kernel(const __hip_bfloat16* __restrict__ in,
                                                         const __hip_bfloat16* __restrict__ wf,
                                                         const float* __restrict__ bias,
                                                         __hip_bfloat16* __restrict__ outp) {
    constexpr int NC = NT * 16 + 4;
    __shared__ short lds[8 * NC * 36];
    const int tid = threadIdx.x;
    const int lane = tid & 63;
    const int wid = tid >> 6;
    const int w0 = blockIdx.x * 4;
    const int b = blockIdx.y;
    const int w = w0 + wid;

    int out_base;
    if (OMODE == 1)
        out_base = ((b * WHALO + w + 2) * DHALO + D0 + 2) * 128;
    else
        out_base = ((b * 64 + w) * 100 + D0) * 128;

    f32x4 acc[NT][8];
#pragma unroll
    for (int n = 0; n < NT; n++)
#pragma unroll
        for (int mi = 0; mi < 8; mi++) acc[n][mi] = (f32x4)0.f;

    const short* inp = (const short*)in;
    const short* wfp = (const short*)wf;

#pragma unroll 1
    for (int cc = 0; cc < 4; cc++) {
        __syncthreads(); // previous-iteration readers done before overwrite
        // stage 8 rows x NC cols x 32 ci (16B chunks)
        for (int c = tid; c < 8 * NC * 4; c += 256) {
            int row = c / (NC * 4);
            int rem = c - row * (NC * 4);
            int col = rem >> 2;
            int jg = rem & 3;
            const uint4 v = *(const uint4*)(inp +
                                            ((size_t)((b * WHALO + w0 + row) * DHALO + D0 + col)) * 128 +
                                            cc * 32 + jg * 8);
            short* lp = &lds[(row * NC + col) * 36 + jg * 8];
            *(uint2*)lp = make_uint2(v.x, v.y);
            *(uint2*)(lp + 4) = make_uint2(v.z, v.w);
        }
        __syncthreads();

#pragma unroll 1
        for (int th = 0; th < 5; th++) {
#pragma unroll
            for (int tw = 0; tw < 5; tw++) {
                const int tap = th * 5 + tw;
                const short* wptr = wfp + ((cc * 25 + tap) * 8) * 512 + lane * 8;
                short8 wfr[8];
#pragma unroll
                for (int mi = 0; mi < 8; mi++) wfr[mi] = *(const short8*)(wptr + mi * 512);

                short8 xfr[NT];
#pragma unroll
                for (int n = 0; n < NT; n++) {
                    const short* lp =
                        &lds[((wid + th) * NC + tw + n * 16 + (lane & 15)) * 36 + (lane >> 4) * 8];
                    uint2 lo = *(const uint2*)lp;
                    uint2 hi = *(const uint2*)(lp + 4);
                    ((uint2*)&xfr[n])[0] = lo;
                    ((uint2*)&xfr[n])[1] = hi;
                }

#pragma unroll
                for (int n = 0; n < NT; n++)
#pragma unroll
                    for (int mi = 0; mi < 8; mi++)
                        acc[n][mi] = __builtin_amdgcn_mfma_f32_16x16x32_bf16(wfr[mi], xfr[n],
                                                                             acc[n][mi], 0, 0, 0);
            }
        }
    }

    unsigned short* outp16 = (unsigned short*)outp;
#pragma unroll
    for (int mi = 0; mi < 8; mi++) {
        const float4 bv = *(const float4*)(bias + mi * 16 + (lane >> 4) * 4);
#pragma unroll
        for (int n = 0; n < NT; n++) {
            const int pix = n * 16 + (lane & 15);
            if (DMASK && (D0 + pix >= 100)) continue;
            f32x4 v = acc[n][mi];
            float v0 = v[0] + bv.x, v1 = v[1] + bv.y, v2 = v[2] + bv.z, v3 = v[3] + bv.w;
            if (RELU) {
                v0 = fmaxf(v0, 0.f); v1 = fmaxf(v1, 0.f);
                v2 = fmaxf(v2, 0.f); v3 = fmaxf(v3, 0.f);
            }
            ushort4 o;
            o.x = f2bf(v0); o.y = f2bf(v1); o.z = f2bf(v2); o.w = f2bf(v3);
            *(ushort4*)(outp16 + out_base + pix * 128 + mi * 16 + (lane >> 4) * 4) = o;
        }
    }
}

// ---------- gather: E (b,TP,128) bf16 -> P4 (b,WHALO,DHALO,128) bf16 interior ----------
__global__ __launch_bounds__(256) void gather_kernel(const __hip_bfloat16* __restrict__ E,
                                                     const int* __restrict__ wb,
                                                     __hip_bfloat16* __restrict__ P) {
    const int w = blockIdx.x;
    const int b = blockIdx.y;
    const int start = wb[(b * W_WORDS + w) * 2 + 0];
    const int end = wb[(b * W_WORDS + w) * 2 + 1];
    const int dur = end - start;
    const int base_e = (b * TP + start + 2) * 128;
    const int base_p = ((b * WHALO + w + 2) * DHALO + 2) * 128;
    const unsigned short* ep = (const unsigned short*)E;
    unsigned short* pp = (unsigned short*)P;
    for (int i = threadIdx.x; i < D_MAX * 64; i += 256) {
        int c2 = (i & 63) * 2;
        int d = i >> 6;
        unsigned int v = (d < dur) ? *(const unsigned int*)(ep + base_e + d * 128 + c2) : 0u;
        *(unsigned int*)(pp + base_p + d * 128 + c2) = v;
    }
}

// ---------- einsum over d + relu: Q (b,64,100,128) bf16 -> xe (b,128,64) fp32 ----------
__global__ __launch_bounds__(128) void einsum_kernel(const __hip_bfloat16* __restrict__ Q,
                                                     const float* __restrict__ lw,
                                                     const float* __restrict__ lb,
                                                     float* __restrict__ xe) {
    const int w = blockIdx.x;
    const int b = blockIdx.y;
    const int c = threadIdx.x;
    const unsigned short* qp = (const unsigned short*)Q + ((b * 64 + w) * 100) * 128 + c;
    float acc = 0.f;
#pragma unroll 4
    for (int d = 0; d < D_MAX; d++) {
        unsigned int u = (unsigned int)qp[d * 128] << 16;
        acc += *reinterpret_cast<float*>(&u) * lw[d];
    }
    xe[(b * 128 + c) * 64 + w] = fmaxf(acc + lb[0], 0.f);
}

// ---------- final conv: xe (b,128,64) fp32 -> out (b,64); only kw==2 column of w6 ----------
__global__ void conv6_kernel(const float* __restrict__ xe, const float* __restrict__ w6,
                             const float* __restrict__ b6, float* __restrict__ out) {
    int b = blockIdx.x;
    int w = threadIdx.x; // 64
    float acc = b6[0];
#pragma unroll 1
    for (int ci = 0; ci < 128; ci++) {
        const float* xr = xe + (b * 128 + ci) * 64;
#pragma unroll
        for (int kh = 0; kh < 5; kh++) {
            int ww = w + kh - 2;
            if ((unsigned)ww < 64u) acc += xr[ww] * w6[ci * 25 + kh * 5 + 2];
        }
    }
    out[b * 64 + w] = acc;
}

extern "C" void kernel_launch(void* const* d_in, const int* in_sizes, int n_in,
                              void* d_out, int out_size, void* d_ws, size_t ws_size,
                              hipStream_t stream) {
    const float* features = (const float*)d_in[0];
    const int* wbnd = (const int*)d_in[1];
    const float* w1 = (const float*)d_in[2];
    const float* b1 = (const float*)d_in[3];
    const float* w2 = (const float*)d_in[4];
    const float* b2 = (const float*)d_in[5];
    const float* w3 = (const float*)d_in[6];
    const float* b3 = (const float*)d_in[7];
    const float* w4 = (const float*)d_in[8];
    const float* b4 = (const float*)d_in[9];
    const float* w5 = (const float*)d_in[10];
    const float* b5 = (const float*)d_in[11];
    const float* lw = (const float*)d_in[12];
    const float* lb = (const float*)d_in[13];
    const float* w6 = (const float*)d_in[14];
    const float* b6 = (const float*)d_in[15];
    float* out = (float*)d_out;

    char* base = (char*)d_ws;
    size_t off = 0;
    auto alloc = [&](size_t bytes) -> char* {
        char* p = base + off;
        off += (bytes + 255) & ~(size_t)255;
        return p;
    };

    __hip_bfloat16* XF = (__hip_bfloat16*)alloc((size_t)BATCH * TP * 96 * 2);
    __hip_bfloat16* Y1 = (__hip_bfloat16*)alloc((size_t)BATCH * TP * 128 * 2);
    __hip_bfloat16* Y2 = (__hip_bfloat16*)alloc((size_t)BATCH * TP * 128 * 2);
    __hip_bfloat16* P4 = (__hip_bfloat16*)alloc((size_t)BATCH * WHALO * DHALO * 128 * 2);
    __hip_bfloat16* P5 = (__hip_bfloat16*)alloc((size_t)BATCH * WHALO * DHALO * 128 * 2);
    float* XE = (float*)alloc((size_t)BATCH * 128 * 64 * 4);
    __hip_bfloat16* WF1 = (__hip_bfloat16*)alloc((size_t)3 * 5 * 8 * 512 * 2);
    __hip_bfloat16* WF2 = (__hip_bfloat16*)alloc((size_t)4 * 5 * 8 * 512 * 2);
    __hip_bfloat16* WF3 = (__hip_bfloat16*)alloc((size_t)4 * 5 * 8 * 512 * 2);
    __hip_bfloat16* WF4 = (__hip_bfloat16*)alloc((size_t)4 * 25 * 8 * 512 * 2);
    __hip_bfloat16* WF5 = (__hip_bfloat16*)alloc((size_t)4 * 25 * 8 * 512 * 2);
    __hip_bfloat16* Q = P4; // conv5 output reuses P4 (dead after conv4)

    // zero halos (and padding channels) — interiors are fully overwritten each call
    hipMemsetAsync(XF, 0, (size_t)BATCH * TP * 96 * 2, stream);
    hipMemsetAsync(Y1, 0, (size_t)BATCH * TP * 128 * 2, stream);
    hipMemsetAsync(Y2, 0, (size_t)BATCH * TP * 128 * 2, stream);
    hipMemsetAsync(P4, 0, (size_t)BATCH * WHALO * DHALO * 128 * 2, stream);
    hipMemsetAsync(P5, 0, (size_t)BATCH * WHALO * DHALO * 128 * 2, stream);

    pack_w_kernel<80, 3, 5><<<240, 256, 0, stream>>>(w1, WF1);
    pack_w_kernel<128, 4, 5><<<320, 256, 0, stream>>>(w2, WF2);
    pack_w_kernel<128, 4, 5><<<320, 256, 0, stream>>>(w3, WF3);
    pack_w_kernel<128, 4, 25><<<1600, 256, 0, stream>>>(w4, WF4);
    pack_w_kernel<128, 4, 25><<<1600, 256, 0, stream>>>(w5, WF5);

    cast_feat_kernel<<<49152, 256, 0, stream>>>(features, XF);

    // conv1d stack (wave = 64 px, all 128 co)
    conv1d_mfma_kernel<96, 3, true><<<dim3(16, 32), 256, 0, stream>>>(XF, WF1, b1, Y1);
    conv1d_mfma_kernel<128, 4, true><<<dim3(16, 32), 256, 0, stream>>>(Y1, WF2, b2, Y2);
    conv1d_mfma_kernel<128, 4, false><<<dim3(16, 32), 256, 0, stream>>>(Y2, WF3, b3, Y1); // E := Y1

    gather_kernel<<<dim3(64, 32), 256, 0, stream>>>(Y1, wbnd, P4);

    // conv4: P4 -> P5 (halo layout). main d 0..63, tail d 64..99 (masked)
    conv2d_lds_kernel<4, true, false, 1, 0><<<dim3(16, 32), 256, 0, stream>>>(P4, WF4, b4, P5);
    conv2d_lds_kernel<3, true, true, 1, 64><<<dim3(16, 32), 256, 0, stream>>>(P4, WF4, b4, P5);

    // conv5: P5 -> Q (compact b,64,100,128)
    conv2d_lds_kernel<4, true, false, 2, 0><<<dim3(16, 32), 256, 0, stream>>>(P5, WF5, b5, Q);
    conv2d_lds_kernel<3, true, true, 2, 64><<<dim3(16, 32), 256, 0, stream>>>(P5, WF5, b5, Q);

    einsum_kernel<<<dim3(64, 32), 128, 0, stream>>>(Q, lw, lb, XE);
    conv6_kernel<<<32, 64, 0, stream>>>(XE, w6, b6, out);
}

// Round 7
// 685.040 us; speedup vs baseline: 1.8014x; 1.3122x over previous
//
#include <hip/hip_runtime.h>
#include <hip/hip_bf16.h>
#include <cstdint>
#include <cstddef>

#define T_LEN 4096
#define TP 4104      // padded t rows: pixel t lives at row t+2; rows 0,1 and 4098..4103 are zero
#define BATCH 32
#define NMELS 80
#define HID 128
#define W_WORDS 64
#define D_MAX 100
#define WHALO 68
#define DHALO 120    // pixel d at halo row d+2; rows 0,1 and 102..119 zero

typedef __attribute__((ext_vector_type(4))) float f32x4;
typedef __attribute__((ext_vector_type(8))) short short8;

static __device__ __forceinline__ unsigned short f2bf(float f) {
    __hip_bfloat16 h = __float2bfloat16(f);
    return *reinterpret_cast<unsigned short*>(&h);
}

// ---------- pack weights into MFMA A-fragment order ----------
// wf[((cc*TAPS + tap)*8 + mi)*512 + lane*8 + j] = w[co][ci][tap], co=mi*16+(lane&15), ci=cc*32+(lane>>4)*8+j
template <int CIN, int CC, int TAPS>
__global__ __launch_bounds__(256) void pack_w_kernel(const float* __restrict__ w,
                                                     __hip_bfloat16* __restrict__ wf) {
    int idx = blockIdx.x * 256 + threadIdx.x; // CC*TAPS*8*64*8
    int r = idx;
    int j = r & 7; r >>= 3;
    int lane = r & 63; r >>= 6;
    int mi = r & 7; r >>= 3;
    int tap = r % TAPS;
    int cc = r / TAPS;
    if (cc >= CC) return;
    int co = mi * 16 + (lane & 15);
    int ci = cc * 32 + (lane >> 4) * 8 + j;
    float v = (ci < CIN) ? w[(co * CIN + ci) * TAPS + tap] : 0.f;
    wf[idx] = __float2bfloat16(v);
}

// ---------- cast features (b,80,t) fp32 -> XF (b,TP,96) bf16, interior rows ----------
__global__ __launch_bounds__(256) void cast_feat_kernel(const float* __restrict__ f,
                                                        __hip_bfloat16* __restrict__ xf) {
    int idx = blockIdx.x * 256 + threadIdx.x; // 32*4096*96
    int c = idx % 96;
    int r = idx / 96;
    int t = r & 4095;
    int b = r >> 12;
    float v = (c < NMELS) ? f[((size_t)b * NMELS + c) * T_LEN + t] : 0.f;
    xf[((size_t)b * TP + t + 2) * 96 + c] = __float2bfloat16(v);
}

// ---------- conv1d MFMA kernel: 512-thread block = 4 px-groups x 2 co-halves ----------
// wave = 64 px x 64 co; co-halves share act cache lines within the block (L1 reuse)
template <int IC, int CC, bool RELU>
__global__ __launch_bounds__(512, 4) void conv1d_mfma_kernel(const __hip_bfloat16* __restrict__ in,
                                                             const __hip_bfloat16* __restrict__ wf,
                                                             const float* __restrict__ bias,
                                                             __hip_bfloat16* __restrict__ outp) {
    const int tid = threadIdx.x;
    const int lane = tid & 63;
    const int wid = tid >> 6;
    const int pxg = wid & 3;
    const int cohalf = wid >> 2;
    const int pix0 = blockIdx.x * 256 + pxg * 64;
    const int b = blockIdx.y;

    const int in_base = (b * TP + pix0) * IC;
    const int out_base = (b * TP + pix0 + 2) * 128;

    f32x4 acc[4][4];
#pragma unroll
    for (int n = 0; n < 4; n++)
#pragma unroll
        for (int mi = 0; mi < 4; mi++) acc[n][mi] = (f32x4)0.f;

    const short* inp = (const short*)in;
    const short* wfp = (const short*)wf;

#pragma unroll 1
    for (int cc = 0; cc < CC; cc++) {
#pragma unroll 1
        for (int th = 0; th < 5; th++) {
            const short* wptr = wfp + ((cc * 5 + th) * 8 + cohalf * 4) * 512 + lane * 8;
            short8 wfr[4];
#pragma unroll
            for (int mi = 0; mi < 4; mi++) wfr[mi] = *(const short8*)(wptr + mi * 512);

            const short* xptr =
                inp + in_base + th * IC + (lane & 15) * IC + (lane >> 4) * 8 + cc * 32;
            short8 xfr[4];
#pragma unroll
            for (int n = 0; n < 4; n++) xfr[n] = *(const short8*)(xptr + n * 16 * IC);

#pragma unroll
            for (int n = 0; n < 4; n++)
#pragma unroll
                for (int mi = 0; mi < 4; mi++)
                    acc[n][mi] =
                        __builtin_amdgcn_mfma_f32_16x16x32_bf16(wfr[mi], xfr[n], acc[n][mi], 0, 0, 0);
        }
    }

    unsigned short* outp16 = (unsigned short*)outp;
#pragma unroll
    for (int mi = 0; mi < 4; mi++) {
        const float4 bv = *(const float4*)(bias + cohalf * 64 + mi * 16 + (lane >> 4) * 4);
#pragma unroll
        for (int n = 0; n < 4; n++) {
            const int pix = n * 16 + (lane & 15);
            f32x4 v = acc[n][mi];
            float v0 = v[0] + bv.x, v1 = v[1] + bv.y, v2 = v[2] + bv.z, v3 = v[3] + bv.w;
            if (RELU) {
                v0 = fmaxf(v0, 0.f); v1 = fmaxf(v1, 0.f);
                v2 = fmaxf(v2, 0.f); v3 = fmaxf(v3, 0.f);
            }
            ushort4 o;
            o.x = f2bf(v0); o.y = f2bf(v1); o.z = f2bf(v2); o.w = f2bf(v3);
            *(ushort4*)(outp16 + out_base + pix * 128 + cohalf * 64 + mi * 16 +
                        (lane >> 4) * 4) = o;
        }
    }
}

// ---------- conv2d MFMA, LDS-staged acts, 512-thread block = 4 w-rows x 2 co-halves ----------
// LDS staged ONCE per block, shared by both co-halves. Merged main+tail: bx>>4 picks
// d-tile (D0 = 0 or 48); stores masked to d<100. OMODE: 1 = halo plane out, 2 = compact out
template <bool RELU, int OMODE>
__global__ __launch_bounds__(512, 4) void conv2d_lds_kernel(const __hip_bfloat16* __restrict__ in,
                                                            const __hip_bfloat16* __restrict__ wf,
                                                            const float* __restrict__ bias,
                                                            __hip_bfloat16* __restrict__ outp) {
    constexpr int NC = 68; // 4*16 + 4
    __shared__ short lds[8 * NC * 36];
    const int tid = threadIdx.x;
    const int lane = tid & 63;
    const int wid = tid >> 6;
    const int wrow = wid & 3;
    const int cohalf = wid >> 2;
    const int w0 = (blockIdx.x & 15) * 4;
    const int D0 = (blockIdx.x >> 4) * 48;
    const int b = blockIdx.y;
    const int w = w0 + wrow;

    int out_base;
    if (OMODE == 1)
        out_base = ((b * WHALO + w + 2) * DHALO + D0 + 2) * 128;
    else
        out_base = ((b * 64 + w) * 100 + D0) * 128;

    f32x4 acc[4][4];
#pragma unroll
    for (int n = 0; n < 4; n++)
#pragma unroll
        for (int mi = 0; mi < 4; mi++) acc[n][mi] = (f32x4)0.f;

    const short* inp = (const short*)in;
    const short* wfp = (const short*)wf;

#pragma unroll 1
    for (int cc = 0; cc < 4; cc++) {
        __syncthreads(); // previous-iteration readers done before overwrite
        // stage 8 rows x NC cols x 32 ci (16B chunks); 2176 chunks over 512 threads
        for (int c = tid; c < 8 * NC * 4; c += 512) {
            int row = c / (NC * 4);
            int rem = c - row * (NC * 4);
            int col = rem >> 2;
            int jg = rem & 3;
            const uint4 v = *(const uint4*)(inp +
                                            ((size_t)((b * WHALO + w0 + row) * DHALO + D0 + col)) * 128 +
                                            cc * 32 + jg * 8);
            short* lp = &lds[(row * NC + col) * 36 + jg * 8];
            *(uint2*)lp = make_uint2(v.x, v.y);
            *(uint2*)(lp + 4) = make_uint2(v.z, v.w);
        }
        __syncthreads();

#pragma unroll 1
        for (int th = 0; th < 5; th++) {
#pragma unroll
            for (int tw = 0; tw < 5; tw++) {
                const int tap = th * 5 + tw;
                const short* wptr = wfp + ((cc * 25 + tap) * 8 + cohalf * 4) * 512 + lane * 8;
                short8 wfr[4];
#pragma unroll
                for (int mi = 0; mi < 4; mi++) wfr[mi] = *(const short8*)(wptr + mi * 512);

                short8 xfr[4];
#pragma unroll
                for (int n = 0; n < 4; n++) {
                    const short* lp =
                        &lds[((wrow + th) * NC + tw + n * 16 + (lane & 15)) * 36 + (lane >> 4) * 8];
                    uint2 lo = *(const uint2*)lp;
                    uint2 hi = *(const uint2*)(lp + 4);
                    ((uint2*)&xfr[n])[0] = lo;
                    ((uint2*)&xfr[n])[1] = hi;
                }

#pragma unroll
                for (int n = 0; n < 4; n++)
#pragma unroll
                    for (int mi = 0; mi < 4; mi++)
                        acc[n][mi] = __builtin_amdgcn_mfma_f32_16x16x32_bf16(wfr[mi], xfr[n],
                                                                             acc[n][mi], 0, 0, 0);
            }
        }
    }

    unsigned short* outp16 = (unsigned short*)outp;
#pragma unroll
    for (int mi = 0; mi < 4; mi++) {
        const float4 bv = *(const float4*)(bias + cohalf * 64 + mi * 16 + (lane >> 4) * 4);
#pragma unroll
        for (int n = 0; n < 4; n++) {
            const int pix = n * 16 + (lane & 15);
            if (D0 + pix >= 100) continue; // mask tail-tile overhang
            f32x4 v = acc[n][mi];
            float v0 = v[0] + bv.x, v1 = v[1] + bv.y, v2 = v[2] + bv.z, v3 = v[3] + bv.w;
            if (RELU) {
                v0 = fmaxf(v0, 0.f); v1 = fmaxf(v1, 0.f);
                v2 = fmaxf(v2, 0.f); v3 = fmaxf(v3, 0.f);
            }
            ushort4 o;
            o.x = f2bf(v0); o.y = f2bf(v1); o.z = f2bf(v2); o.w = f2bf(v3);
            *(ushort4*)(outp16 + out_base + pix * 128 + cohalf * 64 + mi * 16 +
                        (lane >> 4) * 4) = o;
        }
    }
}

// ---------- gather: E (b,TP,128) bf16 -> P4 (b,WHALO,DHALO,128) bf16 interior ----------
__global__ __launch_bounds__(256) void gather_kernel(const __hip_bfloat16* __restrict__ E,
                                                     const int* __restrict__ wb,
                                                     __hip_bfloat16* __restrict__ P) {
    const int w = blockIdx.x;
    const int b = blockIdx.y;
    const int start = wb[(b * W_WORDS + w) * 2 + 0];
    const int end = wb[(b * W_WORDS + w) * 2 + 1];
    const int dur = end - start;
    const int base_e = (b * TP + start + 2) * 128;
    const int base_p = ((b * WHALO + w + 2) * DHALO + 2) * 128;
    const unsigned short* ep = (const unsigned short*)E;
    unsigned short* pp = (unsigned short*)P;
    for (int i = threadIdx.x; i < D_MAX * 64; i += 256) {
        int c2 = (i & 63) * 2;
        int d = i >> 6;
        unsigned int v = (d < dur) ? *(const unsigned int*)(ep + base_e + d * 128 + c2) : 0u;
        *(unsigned int*)(pp + base_p + d * 128 + c2) = v;
    }
}

// ---------- einsum over d + relu: Q (b,64,100,128) bf16 -> xe (b,128,64) fp32 ----------
__global__ __launch_bounds__(128) void einsum_kernel(const __hip_bfloat16* __restrict__ Q,
                                                     const float* __restrict__ lw,
                                                     const float* __restrict__ lb,
                                                     float* __restrict__ xe) {
    const int w = blockIdx.x;
    const int b = blockIdx.y;
    const int c = threadIdx.x;
    const unsigned short* qp = (const unsigned short*)Q + ((b * 64 + w) * 100) * 128 + c;
    float acc = 0.f;
#pragma unroll 4
    for (int d = 0; d < D_MAX; d++) {
        unsigned int u = (unsigned int)qp[d * 128] << 16;
        acc += *reinterpret_cast<float*>(&u) * lw[d];
    }
    xe[(b * 128 + c) * 64 + w] = fmaxf(acc + lb[0], 0.f);
}

// ---------- final conv: xe (b,128,64) fp32 -> out (b,64); only kw==2 column of w6 ----------
__global__ void conv6_kernel(const float* __restrict__ xe, const float* __restrict__ w6,
                             const float* __restrict__ b6, float* __restrict__ out) {
    int b = blockIdx.x;
    int w = threadIdx.x; // 64
    float acc = b6[0];
#pragma unroll 1
    for (int ci = 0; ci < 128; ci++) {
        const float* xr = xe + (b * 128 + ci) * 64;
#pragma unroll
        for (int kh = 0; kh < 5; kh++) {
            int ww = w + kh - 2;
            if ((unsigned)ww < 64u) acc += xr[ww] * w6[ci * 25 + kh * 5 + 2];
        }
    }
    out[b * 64 + w] = acc;
}

extern "C" void kernel_launch(void* const* d_in, const int* in_sizes, int n_in,
                              void* d_out, int out_size, void* d_ws, size_t ws_size,
                              hipStream_t stream) {
    const float* features = (const float*)d_in[0];
    const int* wbnd = (const int*)d_in[1];
    const float* w1 = (const float*)d_in[2];
    const float* b1 = (const float*)d_in[3];
    const float* w2 = (const float*)d_in[4];
    const float* b2 = (const float*)d_in[5];
    const float* w3 = (const float*)d_in[6];
    const float* b3 = (const float*)d_in[7];
    const float* w4 = (const float*)d_in[8];
    const float* b4 = (const float*)d_in[9];
    const float* w5 = (const float*)d_in[10];
    const float* b5 = (const float*)d_in[11];
    const float* lw = (const float*)d_in[12];
    const float* lb = (const float*)d_in[13];
    const float* w6 = (const float*)d_in[14];
    const float* b6 = (const float*)d_in[15];
    float* out = (float*)d_out;

    char* base = (char*)d_ws;
    size_t off = 0;
    auto alloc = [&](size_t bytes) -> char* {
        char* p = base + off;
        off += (bytes + 255) & ~(size_t)255;
        return p;
    };

    __hip_bfloat16* XF = (__hip_bfloat16*)alloc((size_t)BATCH * TP * 96 * 2);
    __hip_bfloat16* Y1 = (__hip_bfloat16*)alloc((size_t)BATCH * TP * 128 * 2);
    __hip_bfloat16* Y2 = (__hip_bfloat16*)alloc((size_t)BATCH * TP * 128 * 2);
    __hip_bfloat16* P4 = (__hip_bfloat16*)alloc((size_t)BATCH * WHALO * DHALO * 128 * 2);
    __hip_bfloat16* P5 = (__hip_bfloat16*)alloc((size_t)BATCH * WHALO * DHALO * 128 * 2);
    float* XE = (float*)alloc((size_t)BATCH * 128 * 64 * 4);
    __hip_bfloat16* WF1 = (__hip_bfloat16*)alloc((size_t)3 * 5 * 8 * 512 * 2);
    __hip_bfloat16* WF2 = (__hip_bfloat16*)alloc((size_t)4 * 5 * 8 * 512 * 2);
    __hip_bfloat16* WF3 = (__hip_bfloat16*)alloc((size_t)4 * 5 * 8 * 512 * 2);
    __hip_bfloat16* WF4 = (__hip_bfloat16*)alloc((size_t)4 * 25 * 8 * 512 * 2);
    __hip_bfloat16* WF5 = (__hip_bfloat16*)alloc((size_t)4 * 25 * 8 * 512 * 2);
    __hip_bfloat16* Q = P4; // conv5 output reuses P4 (dead after conv4)

    // zero halos (and padding channels) — interiors are fully overwritten each call
    hipMemsetAsync(XF, 0, (size_t)BATCH * TP * 96 * 2, stream);
    hipMemsetAsync(Y1, 0, (size_t)BATCH * TP * 128 * 2, stream);
    hipMemsetAsync(Y2, 0, (size_t)BATCH * TP * 128 * 2, stream);
    hipMemsetAsync(P4, 0, (size_t)BATCH * WHALO * DHALO * 128 * 2, stream);
    hipMemsetAsync(P5, 0, (size_t)BATCH * WHALO * DHALO * 128 * 2, stream);

    pack_w_kernel<80, 3, 5><<<240, 256, 0, stream>>>(w1, WF1);
    pack_w_kernel<128, 4, 5><<<320, 256, 0, stream>>>(w2, WF2);
    pack_w_kernel<128, 4, 5><<<320, 256, 0, stream>>>(w3, WF3);
    pack_w_kernel<128, 4, 25><<<1600, 256, 0, stream>>>(w4, WF4);
    pack_w_kernel<128, 4, 25><<<1600, 256, 0, stream>>>(w5, WF5);

    cast_feat_kernel<<<49152, 256, 0, stream>>>(features, XF);

    // conv1d stack: 512-thread blocks (4 px-groups x 2 co-halves)
    conv1d_mfma_kernel<96, 3, true><<<dim3(16, 32), 512, 0, stream>>>(XF, WF1, b1, Y1);
    conv1d_mfma_kernel<128, 4, true><<<dim3(16, 32), 512, 0, stream>>>(Y1, WF2, b2, Y2);
    conv1d_mfma_kernel<128, 4, false><<<dim3(16, 32), 512, 0, stream>>>(Y2, WF3, b3, Y1); // E := Y1

    gather_kernel<<<dim3(64, 32), 256, 0, stream>>>(Y1, wbnd, P4);

    // conv4: P4 -> P5 (halo layout), merged d-tiles (bx>>4: D0=0 | D0=48 masked)
    conv2d_lds_kernel<true, 1><<<dim3(32, 32), 512, 0, stream>>>(P4, WF4, b4, P5);

    // conv5: P5 -> Q (compact b,64,100,128), merged d-tiles
    conv2d_lds_kernel<true, 2><<<dim3(32, 32), 512, 0, stream>>>(P5, WF5, b5, Q);

    einsum_kernel<<<dim3(64, 32), 128, 0, stream>>>(Q, lw, lb, XE);
    conv6_kernel<<<32, 64, 0, stream>>>(XE, w6, b6, out);
}

// Round 9
// 616.077 us; speedup vs baseline: 2.0030x; 1.1119x over previous
//
#include <hip/hip_runtime.h>
#include <hip/hip_bf16.h>
#include <cstdint>
#include <cstddef>

#define T_LEN 4096
#define TP 4104      // padded t rows: pixel t lives at row t+2; rows 0,1 and 4098..4103 are zero
#define BATCH 32
#define NMELS 80
#define HID 128
#define W_WORDS 64
#define D_MAX 100
#define WHALO 68
#define DHALO 120    // pixel d at halo row d+2; rows 0,1 and 102..119 zero

typedef __attribute__((ext_vector_type(4))) float f32x4;
typedef __attribute__((ext_vector_type(8))) short short8;

static __device__ __forceinline__ unsigned short f2bf(float f) {
    __hip_bfloat16 h = __float2bfloat16(f);
    return *reinterpret_cast<unsigned short*>(&h);
}

// ---------- pack weights into MFMA A-fragment order ----------
// wf[((cc*TAPS + tap)*8 + mi)*512 + lane*8 + j] = w[co][ci][tap], co=mi*16+(lane&15), ci=cc*32+(lane>>4)*8+j
template <int CIN, int CC, int TAPS>
__global__ __launch_bounds__(256) void pack_w_kernel(const float* __restrict__ w,
                                                     __hip_bfloat16* __restrict__ wf) {
    int idx = blockIdx.x * 256 + threadIdx.x; // CC*TAPS*8*64*8
    int r = idx;
    int j = r & 7; r >>= 3;
    int lane = r & 63; r >>= 6;
    int mi = r & 7; r >>= 3;
    int tap = r % TAPS;
    int cc = r / TAPS;
    if (cc >= CC) return;
    int co = mi * 16 + (lane & 15);
    int ci = cc * 32 + (lane >> 4) * 8 + j;
    float v = (ci < CIN) ? w[(co * CIN + ci) * TAPS + tap] : 0.f;
    wf[idx] = __float2bfloat16(v);
}

// ---------- cast features (b,80,t) fp32 -> XF (b,TP,96) bf16, interior rows ----------
__global__ __launch_bounds__(256) void cast_feat_kernel(const float* __restrict__ f,
                                                        __hip_bfloat16* __restrict__ xf) {
    int idx = blockIdx.x * 256 + threadIdx.x; // 32*4096*96
    int c = idx % 96;
    int r = idx / 96;
    int t = r & 4095;
    int b = r >> 12;
    float v = (c < NMELS) ? f[((size_t)b * NMELS + c) * T_LEN + t] : 0.f;
    xf[((size_t)b * TP + t + 2) * 96 + c] = __float2bfloat16(v);
}

// ---------- zero the 8 halo t-rows (0,1,4098..4103) of a (b,TP,IC) buffer ----------
template <int IC>
__global__ void zero_rows_kernel(__hip_bfloat16* __restrict__ p) {
    int r = blockIdx.x;            // 0..7
    int b = blockIdx.y;
    int row = (r < 2) ? r : 4096 + r; // 0,1,4098..4103
    ((unsigned short*)p)[((size_t)b * TP + row) * IC + threadIdx.x] = 0;
}

// ---------- zero halo strips of P5 (b,68,120,128) ----------
__global__ __launch_bounds__(256) void zero_p5_halo_kernel(__hip_bfloat16* __restrict__ p) {
    int idx = blockIdx.x * 256 + threadIdx.x; // 32*1760*64
    if (idx >= 32 * 1760 * 64) return;
    int c2 = (idx & 63) * 2;
    int cell = idx >> 6;
    int b = cell / 1760;
    int cl = cell - b * 1760;
    int row, col;
    if (cl < 480) { // rows 0,1,66,67 full width
        int rr = cl / 120;
        row = (rr < 2) ? rr : 64 + rr;
        col = cl - rr * 120;
    } else { // rows 2..65, cols {0,1,102..119}
        int cl2 = cl - 480;
        row = 2 + cl2 / 20;
        int q = cl2 % 20;
        col = (q < 2) ? q : 100 + q;
    }
    *(unsigned int*)((unsigned short*)p + (((size_t)b * WHALO + row) * DHALO + col) * 128 + c2) = 0u;
}

// ---------- conv1d MFMA kernel: 256-thr block = 2 px-groups x 2 co-halves ----------
template <int IC, int CC, bool RELU>
__global__ __launch_bounds__(256, 4) void conv1d_mfma_kernel(const __hip_bfloat16* __restrict__ in,
                                                             const __hip_bfloat16* __restrict__ wf,
                                                             const float* __restrict__ bias,
                                                             __hip_bfloat16* __restrict__ outp) {
    const int tid = threadIdx.x;
    const int lane = tid & 63;
    const int wid = tid >> 6;
    const int pxg = wid & 1;
    const int cohalf = wid >> 1;
    const int pix0 = blockIdx.x * 128 + pxg * 64;
    const int b = blockIdx.y;

    const int in_base = (b * TP + pix0) * IC;
    const int out_base = (b * TP + pix0 + 2) * 128;

    f32x4 acc[4][4];
#pragma unroll
    for (int n = 0; n < 4; n++)
#pragma unroll
        for (int mi = 0; mi < 4; mi++) acc[n][mi] = (f32x4)0.f;

    const short* inp = (const short*)in;
    const short* wfp = (const short*)wf;

#pragma unroll 1
    for (int cc = 0; cc < CC; cc++) {
#pragma unroll 1
        for (int th = 0; th < 5; th++) {
            const short* wptr = wfp + ((cc * 5 + th) * 8 + cohalf * 4) * 512 + lane * 8;
            short8 wfr[4];
#pragma unroll
            for (int mi = 0; mi < 4; mi++) wfr[mi] = *(const short8*)(wptr + mi * 512);

            const short* xptr =
                inp + in_base + th * IC + (lane & 15) * IC + (lane >> 4) * 8 + cc * 32;
            short8 xfr[4];
#pragma unroll
            for (int n = 0; n < 4; n++) xfr[n] = *(const short8*)(xptr + n * 16 * IC);

#pragma unroll
            for (int n = 0; n < 4; n++)
#pragma unroll
                for (int mi = 0; mi < 4; mi++)
                    acc[n][mi] =
                        __builtin_amdgcn_mfma_f32_16x16x32_bf16(wfr[mi], xfr[n], acc[n][mi], 0, 0, 0);
        }
    }

    unsigned short* outp16 = (unsigned short*)outp;
#pragma unroll
    for (int mi = 0; mi < 4; mi++) {
        const float4 bv = *(const float4*)(bias + cohalf * 64 + mi * 16 + (lane >> 4) * 4);
#pragma unroll
        for (int n = 0; n < 4; n++) {
            const int pix = n * 16 + (lane & 15);
            f32x4 v = acc[n][mi];
            float v0 = v[0] + bv.x, v1 = v[1] + bv.y, v2 = v[2] + bv.z, v3 = v[3] + bv.w;
            if (RELU) {
                v0 = fmaxf(v0, 0.f); v1 = fmaxf(v1, 0.f);
                v2 = fmaxf(v2, 0.f); v3 = fmaxf(v3, 0.f);
            }
            ushort4 o;
            o.x = f2bf(v0); o.y = f2bf(v1); o.z = f2bf(v2); o.w = f2bf(v3);
            *(ushort4*)(outp16 + out_base + pix * 128 + cohalf * 64 + mi * 16 +
                        (lane >> 4) * 4) = o;
        }
    }
}

// ---------- conv2d MFMA, LDS-staged acts, 512-thr block = 4 w-rows x 2 co-halves ----------
// LDS layout [jg][row][col] cells of 8 shorts (16B, aligned) -> single ds_read_b128 per frag.
// Merged d-tiles: blockIdx.x>>4 -> D0 = 0 (ntlim=4) or 64 (ntlim=3).
// GATHER: stage from E + word_bounds (fused gather; dur clamped to D_MAX!).
// OMODE: 1 = halo plane out, 2 = compact (b,64,100,128) out
template <bool GATHER, bool RELU, int OMODE>
__global__ __launch_bounds__(512, 4) void conv2d_lds_kernel(const __hip_bfloat16* __restrict__ in,
                                                            const int* __restrict__ wb,
                                                            const __hip_bfloat16* __restrict__ wf,
                                                            const float* __restrict__ bias,
                                                            __hip_bfloat16* __restrict__ outp) {
    __shared__ short lds[4 * 8 * 68 * 8]; // [jg][row][col][8] = 34,816 B
    __shared__ int2 s_sd[8];
    const int tid = threadIdx.x;
    const int lane = tid & 63;
    const int wid = tid >> 6;
    const int wrow = wid & 3;
    const int cohalf = wid >> 2;
    const int w0 = (blockIdx.x & 15) * 4;
    const int dtile = blockIdx.x >> 4;
    const int D0 = dtile * 64;
    const int ntlim = dtile ? 3 : 4;
    const int NCcur = dtile ? 52 : 68;
    const int b = blockIdx.y;
    const int w = w0 + wrow;

    if (GATHER && tid < 8) {
        int wg = w0 + tid - 2;
        int s = 0, du = 0;
        if (wg >= 0 && wg < 64) {
            s = wb[(b * 64 + wg) * 2];
            du = wb[(b * 64 + wg) * 2 + 1] - s;
            if (du > D_MAX) du = D_MAX; // reference masks d < MAX_DUR; words can be longer!
        }
        s_sd[tid] = make_int2(s, du);
    }

    int out_base;
    if (OMODE == 1)
        out_base = ((b * WHALO + w + 2) * DHALO + D0 + 2) * 128;
    else
        out_base = ((b * 64 + w) * 100 + D0) * 128;

    f32x4 acc[4][4];
#pragma unroll
    for (int n = 0; n < 4; n++)
#pragma unroll
        for (int mi = 0; mi < 4; mi++) acc[n][mi] = (f32x4)0.f;

    const short* inp = (const short*)in;
    const short* wfp = (const short*)wf;

#pragma unroll 1
    for (int cc = 0; cc < 4; cc++) {
        __syncthreads(); // prev-iteration readers done (and s_sd visible on cc=0)
        const int nchunks = 8 * NCcur * 4;
        for (int c = tid; c < nchunks; c += 512) {
            int row = c / (NCcur * 4);
            int rem = c - row * (NCcur * 4);
            int col = rem >> 2;
            int jg = rem & 3;
            uint4 v;
            if (GATHER) {
                int d = D0 + col - 2;
                int2 sd = s_sd[row];
                if ((unsigned)d < (unsigned)sd.y)
                    v = *(const uint4*)(inp + ((size_t)(b * TP + 2 + sd.x + d)) * 128 +
                                        cc * 32 + jg * 8);
                else
                    v = make_uint4(0u, 0u, 0u, 0u);
            } else {
                v = *(const uint4*)(inp +
                                    ((size_t)((b * WHALO + w0 + row) * DHALO + D0 + col)) * 128 +
                                    cc * 32 + jg * 8);
            }
            *(uint4*)&lds[((jg * 8 + row) * 68 + col) * 8] = v;
        }
        __syncthreads();

#pragma unroll 1
        for (int th = 0; th < 5; th++) {
#pragma unroll
            for (int tw = 0; tw < 5; tw++) {
                const int tap = th * 5 + tw;
                const short* wptr = wfp + ((cc * 25 + tap) * 8 + cohalf * 4) * 512 + lane * 8;
                short8 wfr[4];
#pragma unroll
                for (int mi = 0; mi < 4; mi++) wfr[mi] = *(const short8*)(wptr + mi * 512);

                short8 xfr[4];
#pragma unroll
                for (int n = 0; n < 4; n++)
                    if (n < ntlim)
                        xfr[n] = *(const short8*)&lds[(((lane >> 4) * 8 + wrow + th) * 68 +
                                                       (tw + n * 16 + (lane & 15))) * 8];

#pragma unroll
                for (int n = 0; n < 4; n++)
                    if (n < ntlim)
#pragma unroll
                        for (int mi = 0; mi < 4; mi++)
                            acc[n][mi] = __builtin_amdgcn_mfma_f32_16x16x32_bf16(
                                wfr[mi], xfr[n], acc[n][mi], 0, 0, 0);
            }
        }
    }

    unsigned short* outp16 = (unsigned short*)outp;
#pragma unroll
    for (int mi = 0; mi < 4; mi++) {
        const float4 bv = *(const float4*)(bias + cohalf * 64 + mi * 16 + (lane >> 4) * 4);
#pragma unroll
        for (int n = 0; n < 4; n++) {
            const int pix = n * 16 + (lane & 15);
            if (D0 + pix >= 100) continue; // tail overhang (also skips n=3 when ntlim=3)
            f32x4 v = acc[n][mi];
            float v0 = v[0] + bv.x, v1 = v[1] + bv.y, v2 = v[2] + bv.z, v3 = v[3] + bv.w;
            if (RELU) {
                v0 = fmaxf(v0, 0.f); v1 = fmaxf(v1, 0.f);
                v2 = fmaxf(v2, 0.f); v3 = fmaxf(v3, 0.f);
            }
            ushort4 o;
            o.x = f2bf(v0); o.y = f2bf(v1); o.z = f2bf(v2); o.w = f2bf(v3);
            *(ushort4*)(outp16 + out_base + pix * 128 + cohalf * 64 + mi * 16 +
                        (lane >> 4) * 4) = o;
        }
    }
}

// ---------- einsum over d + relu: Q (b,64,100,128) bf16 -> xe (b,128,64) fp32 ----------
__global__ __launch_bounds__(128) void einsum_kernel(const __hip_bfloat16* __restrict__ Q,
                                                     const float* __restrict__ lw,
                                                     const float* __restrict__ lb,
                                                     float* __restrict__ xe) {
    const int w = blockIdx.x;
    const int b = blockIdx.y;
    const int c = threadIdx.x;
    const unsigned short* qp = (const unsigned short*)Q + ((b * 64 + w) * 100) * 128 + c;
    float acc = 0.f;
#pragma unroll 4
    for (int d = 0; d < D_MAX; d++) {
        unsigned int u = (unsigned int)qp[d * 128] << 16;
        acc += *reinterpret_cast<float*>(&u) * lw[d];
    }
    xe[(b * 128 + c) * 64 + w] = fmaxf(acc + lb[0], 0.f);
}

// ---------- final conv: xe (b,128,64) fp32 -> out (b,64); only kw==2 column of w6 ----------
__global__ void conv6_kernel(const float* __restrict__ xe, const float* __restrict__ w6,
                             const float* __restrict__ b6, float* __restrict__ out) {
    int b = blockIdx.x;
    int w = threadIdx.x; // 64
    float acc = b6[0];
#pragma unroll 1
    for (int ci = 0; ci < 128; ci++) {
        const float* xr = xe + (b * 128 + ci) * 64;
#pragma unroll
        for (int kh = 0; kh < 5; kh++) {
            int ww = w + kh - 2;
            if ((unsigned)ww < 64u) acc += xr[ww] * w6[ci * 25 + kh * 5 + 2];
        }
    }
    out[b * 64 + w] = acc;
}

extern "C" void kernel_launch(void* const* d_in, const int* in_sizes, int n_in,
                              void* d_out, int out_size, void* d_ws, size_t ws_size,
                              hipStream_t stream) {
    const float* features = (const float*)d_in[0];
    const int* wbnd = (const int*)d_in[1];
    const float* w1 = (const float*)d_in[2];
    const float* b1 = (const float*)d_in[3];
    const float* w2 = (const float*)d_in[4];
    const float* b2 = (const float*)d_in[5];
    const float* w3 = (const float*)d_in[6];
    const float* b3 = (const float*)d_in[7];
    const float* w4 = (const float*)d_in[8];
    const float* b4 = (const float*)d_in[9];
    const float* w5 = (const float*)d_in[10];
    const float* b5 = (const float*)d_in[11];
    const float* lw = (const float*)d_in[12];
    const float* lb = (const float*)d_in[13];
    const float* w6 = (const float*)d_in[14];
    const float* b6 = (const float*)d_in[15];
    float* out = (float*)d_out;

    char* base = (char*)d_ws;
    size_t off = 0;
    auto alloc = [&](size_t bytes) -> char* {
        char* p = base + off;
        off += (bytes + 255) & ~(size_t)255;
        return p;
    };

    __hip_bfloat16* XF = (__hip_bfloat16*)alloc((size_t)BATCH * TP * 96 * 2);
    __hip_bfloat16* Y1 = (__hip_bfloat16*)alloc((size_t)BATCH * TP * 128 * 2);
    __hip_bfloat16* Y2 = (__hip_bfloat16*)alloc((size_t)BATCH * TP * 128 * 2);
    __hip_bfloat16* P5 = (__hip_bfloat16*)alloc((size_t)BATCH * WHALO * DHALO * 128 * 2);
    __hip_bfloat16* Q  = (__hip_bfloat16*)alloc((size_t)BATCH * 64 * 100 * 128 * 2);
    float* XE = (float*)alloc((size_t)BATCH * 128 * 64 * 4);
    __hip_bfloat16* WF1 = (__hip_bfloat16*)alloc((size_t)3 * 5 * 8 * 512 * 2);
    __hip_bfloat16* WF2 = (__hip_bfloat16*)alloc((size_t)4 * 5 * 8 * 512 * 2);
    __hip_bfloat16* WF3 = (__hip_bfloat16*)alloc((size_t)4 * 5 * 8 * 512 * 2);
    __hip_bfloat16* WF4 = (__hip_bfloat16*)alloc((size_t)4 * 25 * 8 * 512 * 2);
    __hip_bfloat16* WF5 = (__hip_bfloat16*)alloc((size_t)4 * 25 * 8 * 512 * 2);

    // zero halo rows/strips (interiors fully overwritten each call)
    zero_rows_kernel<96><<<dim3(8, 32), 96, 0, stream>>>(XF);
    zero_rows_kernel<128><<<dim3(8, 32), 128, 0, stream>>>(Y1);
    zero_rows_kernel<128><<<dim3(8, 32), 128, 0, stream>>>(Y2);
    zero_p5_halo_kernel<<<14080, 256, 0, stream>>>(P5);

    pack_w_kernel<80, 3, 5><<<240, 256, 0, stream>>>(w1, WF1);
    pack_w_kernel<128, 4, 5><<<320, 256, 0, stream>>>(w2, WF2);
    pack_w_kernel<128, 4, 5><<<320, 256, 0, stream>>>(w3, WF3);
    pack_w_kernel<128, 4, 25><<<1600, 256, 0, stream>>>(w4, WF4);
    pack_w_kernel<128, 4, 25><<<1600, 256, 0, stream>>>(w5, WF5);

    cast_feat_kernel<<<49152, 256, 0, stream>>>(features, XF);

    // conv1d stack: 256-thr blocks (2 px-groups x 2 co-halves)
    conv1d_mfma_kernel<96, 3, true><<<dim3(32, 32), 256, 0, stream>>>(XF, WF1, b1, Y1);
    conv1d_mfma_kernel<128, 4, true><<<dim3(32, 32), 256, 0, stream>>>(Y1, WF2, b2, Y2);
    conv1d_mfma_kernel<128, 4, false><<<dim3(32, 32), 256, 0, stream>>>(Y2, WF3, b3, Y1); // E := Y1

    // conv4: gather fused into staging; E -> P5 (halo plane)
    conv2d_lds_kernel<true, true, 1><<<dim3(32, 32), 512, 0, stream>>>(Y1, wbnd, WF4, b4, P5);

    // conv5: P5 -> Q (compact)
    conv2d_lds_kernel<false, true, 2><<<dim3(32, 32), 512, 0, stream>>>(P5, wbnd, WF5, b5, Q);

    einsum_kernel<<<dim3(64, 32), 128, 0, stream>>>(Q, lw, lb, XE);
    conv6_kernel<<<32, 64, 0, stream>>>(XE, w6, b6, out);
}

// Round 10
// 572.672 us; speedup vs baseline: 2.1548x; 1.0758x over previous
//
#include <hip/hip_runtime.h>
#include <hip/hip_bf16.h>
#include <cstdint>
#include <cstddef>

#define T_LEN 4096
#define TP 4104      // padded t rows: pixel t lives at row t+2; rows 0,1 and 4098..4103 are zero
#define BATCH 32
#define NMELS 80
#define HID 128
#define W_WORDS 64
#define D_MAX 100
#define WHALO 68
#define DHALO 120    // pixel d at halo row d+2; rows 0,1 and 102..119 zero

typedef __attribute__((ext_vector_type(4))) float f32x4;
typedef __attribute__((ext_vector_type(8))) short short8;

static __device__ __forceinline__ unsigned short f2bf(float f) {
    __hip_bfloat16 h = __float2bfloat16(f);
    return *reinterpret_cast<unsigned short*>(&h);
}

// ---------- pack weights into MFMA A-fragment order ----------
// wf[((cc*TAPS + tap)*8 + mi)*512 + lane*8 + j] = w[co][ci][tap], co=mi*16+(lane&15), ci=cc*32+(lane>>4)*8+j
template <int CIN, int CC, int TAPS>
__global__ __launch_bounds__(256) void pack_w_kernel(const float* __restrict__ w,
                                                     __hip_bfloat16* __restrict__ wf) {
    int idx = blockIdx.x * 256 + threadIdx.x; // CC*TAPS*8*64*8
    int r = idx;
    int j = r & 7; r >>= 3;
    int lane = r & 63; r >>= 6;
    int mi = r & 7; r >>= 3;
    int tap = r % TAPS;
    int cc = r / TAPS;
    if (cc >= CC) return;
    int co = mi * 16 + (lane & 15);
    int ci = cc * 32 + (lane >> 4) * 8 + j;
    float v = (ci < CIN) ? w[(co * CIN + ci) * TAPS + tap] : 0.f;
    wf[idx] = __float2bfloat16(v);
}

// ---------- cast features: tiled LDS transpose (b,80,t) fp32 -> XF (b,TP,96) bf16 ----------
// block = 64 t x 96 c tile; coalesced f32x4 reads along t, coalesced ushort4 writes along c
__global__ __launch_bounds__(256) void cast_feat_kernel(const float* __restrict__ f,
                                                        __hip_bfloat16* __restrict__ xf) {
    __shared__ unsigned short lds[64 * 100]; // [t_local][c] c-padded to 100
    const int tid = threadIdx.x;
    const int t0 = blockIdx.x * 64;
    const int b = blockIdx.y;

#pragma unroll
    for (int k = 0; k < 6; k++) {
        int idx = tid + k * 256;       // < 1536
        int f4 = idx & 15;             // t-quad
        int c = idx >> 4;              // 0..95
        float4 v = make_float4(0.f, 0.f, 0.f, 0.f);
        if (c < NMELS)
            v = *(const float4*)(f + ((size_t)b * NMELS + c) * T_LEN + t0 + f4 * 4);
        lds[(f4 * 4 + 0) * 100 + c] = f2bf(v.x);
        lds[(f4 * 4 + 1) * 100 + c] = f2bf(v.y);
        lds[(f4 * 4 + 2) * 100 + c] = f2bf(v.z);
        lds[(f4 * 4 + 3) * 100 + c] = f2bf(v.w);
    }
    __syncthreads();
    unsigned short* xp = (unsigned short*)xf;
#pragma unroll
    for (int k = 0; k < 6; k++) {
        int idx = tid + k * 256;       // < 1536
        int tl = idx / 24;
        int cq = idx - tl * 24;        // 0..23
        ushort4 o;
        o.x = lds[tl * 100 + cq * 4 + 0];
        o.y = lds[tl * 100 + cq * 4 + 1];
        o.z = lds[tl * 100 + cq * 4 + 2];
        o.w = lds[tl * 100 + cq * 4 + 3];
        *(ushort4*)(xp + ((size_t)b * TP + t0 + tl + 2) * 96 + cq * 4) = o;
    }
}

// ---------- zero the 8 halo t-rows (0,1,4098..4103) of a (b,TP,IC) buffer ----------
template <int IC>
__global__ void zero_rows_kernel(__hip_bfloat16* __restrict__ p) {
    int r = blockIdx.x;            // 0..7
    int b = blockIdx.y;
    int row = (r < 2) ? r : 4096 + r; // 0,1,4098..4103
    ((unsigned short*)p)[((size_t)b * TP + row) * IC + threadIdx.x] = 0;
}

// ---------- zero halo strips of P5 (b,68,120,128) ----------
__global__ __launch_bounds__(256) void zero_p5_halo_kernel(__hip_bfloat16* __restrict__ p) {
    int idx = blockIdx.x * 256 + threadIdx.x; // 32*1760*64
    if (idx >= 32 * 1760 * 64) return;
    int c2 = (idx & 63) * 2;
    int cell = idx >> 6;
    int b = cell / 1760;
    int cl = cell - b * 1760;
    int row, col;
    if (cl < 480) { // rows 0,1,66,67 full width
        int rr = cl / 120;
        row = (rr < 2) ? rr : 64 + rr;
        col = cl - rr * 120;
    } else { // rows 2..65, cols {0,1,102..119}
        int cl2 = cl - 480;
        row = 2 + cl2 / 20;
        int q = cl2 % 20;
        col = (q < 2) ? q : 100 + q;
    }
    *(unsigned int*)((unsigned short*)p + (((size_t)b * WHALO + row) * DHALO + col) * 128 + c2) = 0u;
}

// ---------- conv1d MFMA, LDS-staged + double-buffered ----------
// 256-thr block = 2 px-groups x 2 co-halves; block covers 128 px (+4 halo).
// LDS cells [jg(4)][col(136 pad)] of 8 shorts; dbuf: load cc+1 early, ds_write after compute.
template <int IC, int CC, bool RELU>
__global__ __launch_bounds__(256, 4) void conv1d_mfma_kernel(const __hip_bfloat16* __restrict__ in,
                                                             const __hip_bfloat16* __restrict__ wf,
                                                             const float* __restrict__ bias,
                                                             __hip_bfloat16* __restrict__ outp) {
    __shared__ short lds[2][4 * 136 * 8]; // 2 x 8704 B
    const int tid = threadIdx.x;
    const int lane = tid & 63;
    const int wid = tid >> 6;
    const int pxg = wid & 1;
    const int cohalf = wid >> 1;
    const int pix0b = blockIdx.x * 128;
    const int b = blockIdx.y;

    const short* inp = (const short*)in;
    const short* wfp = (const short*)wf;

    uint4 v[3];
    auto loadcc = [&](int cc) {
#pragma unroll
        for (int k = 0; k < 3; k++) {
            int c = tid + (k << 8);
            if (c < 528) {
                int jg = c & 3, col = c >> 2; // col 0..131 -> t-row pix0b+col
                v[k] = *(const uint4*)(inp + ((size_t)(b * TP + pix0b + col)) * IC + cc * 32 +
                                       jg * 8);
            }
        }
    };
    auto writecc = [&](int buf) {
#pragma unroll
        for (int k = 0; k < 3; k++) {
            int c = tid + (k << 8);
            if (c < 528) {
                int jg = c & 3, col = c >> 2;
                *(uint4*)&lds[buf][(jg * 136 + col) * 8] = v[k];
            }
        }
    };

    f32x4 acc[4][4];
#pragma unroll
    for (int n = 0; n < 4; n++)
#pragma unroll
        for (int mi = 0; mi < 4; mi++) acc[n][mi] = (f32x4)0.f;

    loadcc(0);
    writecc(0);

#pragma unroll 1
    for (int cc = 0; cc < CC; cc++) {
        __syncthreads(); // publish buf[cc&1]
        if (cc + 1 < CC) loadcc(cc + 1);
        const short* lb = lds[cc & 1];
#pragma unroll 1
        for (int th = 0; th < 5; th++) {
            const short* wptr = wfp + ((cc * 5 + th) * 8 + cohalf * 4) * 512 + lane * 8;
            short8 wfr[4];
#pragma unroll
            for (int mi = 0; mi < 4; mi++) wfr[mi] = *(const short8*)(wptr + mi * 512);

            short8 xfr[4];
#pragma unroll
            for (int n = 0; n < 4; n++)
                xfr[n] = *(const short8*)&lb[((lane >> 4) * 136 + pxg * 64 + th + n * 16 +
                                              (lane & 15)) * 8];

#pragma unroll
            for (int n = 0; n < 4; n++)
#pragma unroll
                for (int mi = 0; mi < 4; mi++)
                    acc[n][mi] =
                        __builtin_amdgcn_mfma_f32_16x16x32_bf16(wfr[mi], xfr[n], acc[n][mi], 0, 0, 0);
        }
        if (cc + 1 < CC) writecc((cc + 1) & 1);
    }

    const int out_base = (b * TP + pix0b + pxg * 64 + 2) * 128;
    unsigned short* outp16 = (unsigned short*)outp;
#pragma unroll
    for (int mi = 0; mi < 4; mi++) {
        const float4 bv = *(const float4*)(bias + cohalf * 64 + mi * 16 + (lane >> 4) * 4);
#pragma unroll
        for (int n = 0; n < 4; n++) {
            const int pix = n * 16 + (lane & 15);
            f32x4 a = acc[n][mi];
            float v0 = a[0] + bv.x, v1 = a[1] + bv.y, v2 = a[2] + bv.z, v3 = a[3] + bv.w;
            if (RELU) {
                v0 = fmaxf(v0, 0.f); v1 = fmaxf(v1, 0.f);
                v2 = fmaxf(v2, 0.f); v3 = fmaxf(v3, 0.f);
            }
            ushort4 o;
            o.x = f2bf(v0); o.y = f2bf(v1); o.z = f2bf(v2); o.w = f2bf(v3);
            *(ushort4*)(outp16 + out_base + pix * 128 + cohalf * 64 + mi * 16 +
                        (lane >> 4) * 4) = o;
        }
    }
}

// ---------- conv2d MFMA, LDS-staged + double-buffered, 512-thr block ----------
// Block = 4 w-rows x 2 co-halves; LDS cells [jg(4)][row(8)][col(68)] of 16B, x2 buffers.
// Merged d-tiles: blockIdx.x>>4 -> D0=0 (ntlim=4) or 64 (ntlim=3, NC=52).
// GATHER: stage from E + word_bounds (dur clamped to D_MAX). OMODE: 1=halo out, 2=compact out
template <bool GATHER, bool RELU, int OMODE>
__global__ __launch_bounds__(512, 3) void conv2d_lds_kernel(const __hip_bfloat16* __restrict__ in,
                                                            const int* __restrict__ wb,
                                                            const __hip_bfloat16* __restrict__ wf,
                                                            const float* __restrict__ bias,
                                                            __hip_bfloat16* __restrict__ outp) {
    __shared__ short lds[2][4 * 8 * 68 * 8]; // 2 x 34,816 B
    __shared__ int2 s_sd[8];
    const int tid = threadIdx.x;
    const int lane = tid & 63;
    const int wid = tid >> 6;
    const int wrow = wid & 3;
    const int cohalf = wid >> 2;
    const int w0 = (blockIdx.x & 15) * 4;
    const int dtile = blockIdx.x >> 4;
    const int D0 = dtile * 64;
    const int ntlim = dtile ? 3 : 4;
    const int b = blockIdx.y;
    const int w = w0 + wrow;

    if (GATHER && tid < 8) {
        int wg = w0 + tid - 2;
        int s = 0, du = 0;
        if (wg >= 0 && wg < 64) {
            s = wb[(b * 64 + wg) * 2];
            du = wb[(b * 64 + wg) * 2 + 1] - s;
            if (du > D_MAX) du = D_MAX; // reference masks d < MAX_DUR
        }
        s_sd[tid] = make_int2(s, du);
    }
    __syncthreads(); // s_sd visible before prologue staging

    const short* inp = (const short*)in;
    const short* wfp = (const short*)wf;

    uint4 v[5];
    auto loadcc = [&](int cc) {
        const int nchunks = dtile ? (8 * 52 * 4) : (8 * 68 * 4);
#pragma unroll
        for (int k = 0; k < 5; k++) {
            int c = tid + (k << 9);
            if (c < nchunks) {
                int row, rem;
                if (dtile == 0) { row = c / 272; rem = c - row * 272; }
                else            { row = c / 208; rem = c - row * 208; }
                int col = rem >> 2;
                int jg = rem & 3;
                if (GATHER) {
                    int d = D0 + col - 2;
                    int2 sd = s_sd[row];
                    if ((unsigned)d < (unsigned)sd.y)
                        v[k] = *(const uint4*)(inp + ((size_t)(b * TP + 2 + sd.x + d)) * 128 +
                                               cc * 32 + jg * 8);
                    else
                        v[k] = make_uint4(0u, 0u, 0u, 0u);
                } else {
                    v[k] = *(const uint4*)(inp +
                                           ((size_t)((b * WHALO + w0 + row) * DHALO + D0 + col)) *
                                               128 + cc * 32 + jg * 8);
                }
            }
        }
    };
    auto writecc = [&](int buf) {
        const int nchunks = dtile ? (8 * 52 * 4) : (8 * 68 * 4);
#pragma unroll
        for (int k = 0; k < 5; k++) {
            int c = tid + (k << 9);
            if (c < nchunks) {
                int row, rem;
                if (dtile == 0) { row = c / 272; rem = c - row * 272; }
                else            { row = c / 208; rem = c - row * 208; }
                int col = rem >> 2;
                int jg = rem & 3;
                *(uint4*)&lds[buf][((jg * 8 + row) * 68 + col) * 8] = v[k];
            }
        }
    };

    f32x4 acc[4][4];
#pragma unroll
    for (int n = 0; n < 4; n++)
#pragma unroll
        for (int mi = 0; mi < 4; mi++) acc[n][mi] = (f32x4)0.f;

    loadcc(0);
    writecc(0);

#pragma unroll 1
    for (int cc = 0; cc < 4; cc++) {
        __syncthreads(); // publish buf[cc&1]
        if (cc < 3) loadcc(cc + 1);
        const short* lbuf = lds[cc & 1];
#pragma unroll 1
        for (int th = 0; th < 5; th++) {
#pragma unroll
            for (int tw = 0; tw < 5; tw++) {
                const int tap = th * 5 + tw;
                const short* wptr = wfp + ((cc * 25 + tap) * 8 + cohalf * 4) * 512 + lane * 8;
                short8 wfr[4];
#pragma unroll
                for (int mi = 0; mi < 4; mi++) wfr[mi] = *(const short8*)(wptr + mi * 512);

                short8 xfr[4];
#pragma unroll
                for (int n = 0; n < 4; n++)
                    if (n < ntlim)
                        xfr[n] = *(const short8*)&lbuf[(((lane >> 4) * 8 + wrow + th) * 68 +
                                                        (tw + n * 16 + (lane & 15))) * 8];

#pragma unroll
                for (int n = 0; n < 4; n++)
                    if (n < ntlim)
#pragma unroll
                        for (int mi = 0; mi < 4; mi++)
                            acc[n][mi] = __builtin_amdgcn_mfma_f32_16x16x32_bf16(
                                wfr[mi], xfr[n], acc[n][mi], 0, 0, 0);
            }
        }
        if (cc < 3) writecc((cc + 1) & 1);
    }

    int out_base;
    if (OMODE == 1)
        out_base = ((b * WHALO + w + 2) * DHALO + D0 + 2) * 128;
    else
        out_base = ((b * 64 + w) * 100 + D0) * 128;

    unsigned short* outp16 = (unsigned short*)outp;
#pragma unroll
    for (int mi = 0; mi < 4; mi++) {
        const float4 bv = *(const float4*)(bias + cohalf * 64 + mi * 16 + (lane >> 4) * 4);
#pragma unroll
        for (int n = 0; n < 4; n++) {
            const int pix = n * 16 + (lane & 15);
            if (D0 + pix >= 100) continue; // tail overhang (also skips n=3 when ntlim=3)
            f32x4 a = acc[n][mi];
            float v0 = a[0] + bv.x, v1 = a[1] + bv.y, v2 = a[2] + bv.z, v3 = a[3] + bv.w;
            if (RELU) {
                v0 = fmaxf(v0, 0.f); v1 = fmaxf(v1, 0.f);
                v2 = fmaxf(v2, 0.f); v3 = fmaxf(v3, 0.f);
            }
            ushort4 o;
            o.x = f2bf(v0); o.y = f2bf(v1); o.z = f2bf(v2); o.w = f2bf(v3);
            *(ushort4*)(outp16 + out_base + pix * 128 + cohalf * 64 + mi * 16 +
                        (lane >> 4) * 4) = o;
        }
    }
}

// ---------- einsum over d + relu: Q (b,64,100,128) bf16 -> xe (b,128,64) fp32 ----------
__global__ __launch_bounds__(128) void einsum_kernel(const __hip_bfloat16* __restrict__ Q,
                                                     const float* __restrict__ lw,
                                                     const float* __restrict__ lb,
                                                     float* __restrict__ xe) {
    const int w = blockIdx.x;
    const int b = blockIdx.y;
    const int c = threadIdx.x;
    const unsigned short* qp = (const unsigned short*)Q + ((b * 64 + w) * 100) * 128 + c;
    float acc = 0.f;
#pragma unroll 4
    for (int d = 0; d < D_MAX; d++) {
        unsigned int u = (unsigned int)qp[d * 128] << 16;
        acc += *reinterpret_cast<float*>(&u) * lw[d];
    }
    xe[(b * 128 + c) * 64 + w] = fmaxf(acc + lb[0], 0.f);
}

// ---------- final conv: xe (b,128,64) fp32 -> out (b,64); only kw==2 column of w6 ----------
__global__ void conv6_kernel(const float* __restrict__ xe, const float* __restrict__ w6,
                             const float* __restrict__ b6, float* __restrict__ out) {
    int b = blockIdx.x;
    int w = threadIdx.x; // 64
    float acc = b6[0];
#pragma unroll 1
    for (int ci = 0; ci < 128; ci++) {
        const float* xr = xe + (b * 128 + ci) * 64;
#pragma unroll
        for (int kh = 0; kh < 5; kh++) {
            int ww = w + kh - 2;
            if ((unsigned)ww < 64u) acc += xr[ww] * w6[ci * 25 + kh * 5 + 2];
        }
    }
    out[b * 64 + w] = acc;
}

extern "C" void kernel_launch(void* const* d_in, const int* in_sizes, int n_in,
                              void* d_out, int out_size, void* d_ws, size_t ws_size,
                              hipStream_t stream) {
    const float* features = (const float*)d_in[0];
    const int* wbnd = (const int*)d_in[1];
    const float* w1 = (const float*)d_in[2];
    const float* b1 = (const float*)d_in[3];
    const float* w2 = (const float*)d_in[4];
    const float* b2 = (const float*)d_in[5];
    const float* w3 = (const float*)d_in[6];
    const float* b3 = (const float*)d_in[7];
    const float* w4 = (const float*)d_in[8];
    const float* b4 = (const float*)d_in[9];
    const float* w5 = (const float*)d_in[10];
    const float* b5 = (const float*)d_in[11];
    const float* lw = (const float*)d_in[12];
    const float* lb = (const float*)d_in[13];
    const float* w6 = (const float*)d_in[14];
    const float* b6 = (const float*)d_in[15];
    float* out = (float*)d_out;

    char* base = (char*)d_ws;
    size_t off = 0;
    auto alloc = [&](size_t bytes) -> char* {
        char* p = base + off;
        off += (bytes + 255) & ~(size_t)255;
        return p;
    };

    __hip_bfloat16* XF = (__hip_bfloat16*)alloc((size_t)BATCH * TP * 96 * 2);
    __hip_bfloat16* Y1 = (__hip_bfloat16*)alloc((size_t)BATCH * TP * 128 * 2);
    __hip_bfloat16* Y2 = (__hip_bfloat16*)alloc((size_t)BATCH * TP * 128 * 2);
    __hip_bfloat16* P5 = (__hip_bfloat16*)alloc((size_t)BATCH * WHALO * DHALO * 128 * 2);
    __hip_bfloat16* Q  = (__hip_bfloat16*)alloc((size_t)BATCH * 64 * 100 * 128 * 2);
    float* XE = (float*)alloc((size_t)BATCH * 128 * 64 * 4);
    __hip_bfloat16* WF1 = (__hip_bfloat16*)alloc((size_t)3 * 5 * 8 * 512 * 2);
    __hip_bfloat16* WF2 = (__hip_bfloat16*)alloc((size_t)4 * 5 * 8 * 512 * 2);
    __hip_bfloat16* WF3 = (__hip_bfloat16*)alloc((size_t)4 * 5 * 8 * 512 * 2);
    __hip_bfloat16* WF4 = (__hip_bfloat16*)alloc((size_t)4 * 25 * 8 * 512 * 2);
    __hip_bfloat16* WF5 = (__hip_bfloat16*)alloc((size_t)4 * 25 * 8 * 512 * 2);

    // zero halo rows/strips (interiors fully overwritten each call)
    zero_rows_kernel<96><<<dim3(8, 32), 96, 0, stream>>>(XF);
    zero_rows_kernel<128><<<dim3(8, 32), 128, 0, stream>>>(Y1);
    zero_rows_kernel<128><<<dim3(8, 32), 128, 0, stream>>>(Y2);
    zero_p5_halo_kernel<<<14080, 256, 0, stream>>>(P5);

    pack_w_kernel<80, 3, 5><<<240, 256, 0, stream>>>(w1, WF1);
    pack_w_kernel<128, 4, 5><<<320, 256, 0, stream>>>(w2, WF2);
    pack_w_kernel<128, 4, 5><<<320, 256, 0, stream>>>(w3, WF3);
    pack_w_kernel<128, 4, 25><<<1600, 256, 0, stream>>>(w4, WF4);
    pack_w_kernel<128, 4, 25><<<1600, 256, 0, stream>>>(w5, WF5);

    cast_feat_kernel<<<dim3(64, 32), 256, 0, stream>>>(features, XF);

    // conv1d stack: 256-thr blocks, LDS dbuf; block = 128 px
    conv1d_mfma_kernel<96, 3, true><<<dim3(32, 32), 256, 0, stream>>>(XF, WF1, b1, Y1);
    conv1d_mfma_kernel<128, 4, true><<<dim3(32, 32), 256, 0, stream>>>(Y1, WF2, b2, Y2);
    conv1d_mfma_kernel<128, 4, false><<<dim3(32, 32), 256, 0, stream>>>(Y2, WF3, b3, Y1); // E := Y1

    // conv4: gather fused into staging; E -> P5 (halo plane)
    conv2d_lds_kernel<true, true, 1><<<dim3(32, 32), 512, 0, stream>>>(Y1, wbnd, WF4, b4, P5);

    // conv5: P5 -> Q (compact)
    conv2d_lds_kernel<false, true, 2><<<dim3(32, 32), 512, 0, stream>>>(P5, wbnd, WF5, b5, Q);

    einsum_kernel<<<dim3(64, 32), 128, 0, stream>>>(Q, lw, lb, XE);
    conv6_kernel<<<32, 64, 0, stream>>>(XE, w6, b6, out);
}

// Round 11
// 541.572 us; speedup vs baseline: 2.2785x; 1.0574x over previous
//
#include <hip/hip_runtime.h>
#include <hip/hip_bf16.h>
#include <cstdint>
#include <cstddef>

#define T_LEN 4096
#define TP 4104      // padded t rows: pixel t lives at row t+2; rows 0,1 and 4098..4103 are zero
#define BATCH 32
#define NMELS 80
#define HID 128
#define W_WORDS 64
#define D_MAX 100
#define WHALO 68
#define DHALO 120    // pixel d at halo row d+2; rows 0,1 and 102..119 zero

typedef __attribute__((ext_vector_type(4))) float f32x4;
typedef __attribute__((ext_vector_type(8))) short short8;

static __device__ __forceinline__ unsigned short f2bf(float f) {
    __hip_bfloat16 h = __float2bfloat16(f);
    return *reinterpret_cast<unsigned short*>(&h);
}

// async global->LDS DMA, 16B per lane; dest = wave-uniform base + lane*16
typedef const __attribute__((address_space(1))) unsigned int* as1_u32p;
typedef __attribute__((address_space(3))) unsigned int* as3_u32p;
static __device__ __forceinline__ void gload16(const void* g, void* l) {
    __builtin_amdgcn_global_load_lds((as1_u32p)(uintptr_t)g, (as3_u32p)(uintptr_t)l, 16, 0, 0);
}

// ---------- pack weights into MFMA A-fragment order ----------
// wf[((cc*TAPS + tap)*8 + mi)*512 + lane*8 + j] = w[co][ci][tap], co=mi*16+(lane&15), ci=cc*32+(lane>>4)*8+j
template <int CIN, int CC, int TAPS>
__global__ __launch_bounds__(256) void pack_w_kernel(const float* __restrict__ w,
                                                     __hip_bfloat16* __restrict__ wf) {
    int idx = blockIdx.x * 256 + threadIdx.x; // CC*TAPS*8*64*8
    int r = idx;
    int j = r & 7; r >>= 3;
    int lane = r & 63; r >>= 6;
    int mi = r & 7; r >>= 3;
    int tap = r % TAPS;
    int cc = r / TAPS;
    if (cc >= CC) return;
    int co = mi * 16 + (lane & 15);
    int ci = cc * 32 + (lane >> 4) * 8 + j;
    float v = (ci < CIN) ? w[(co * CIN + ci) * TAPS + tap] : 0.f;
    wf[idx] = __float2bfloat16(v);
}

// ---------- cast features: tiled LDS transpose (b,80,t) fp32 -> XF (b,TP,96) bf16 ----------
__global__ __launch_bounds__(256) void cast_feat_kernel(const float* __restrict__ f,
                                                        __hip_bfloat16* __restrict__ xf) {
    __shared__ unsigned short lds[64 * 100]; // [t_local][c] c-padded to 100
    const int tid = threadIdx.x;
    const int t0 = blockIdx.x * 64;
    const int b = blockIdx.y;

#pragma unroll
    for (int k = 0; k < 6; k++) {
        int idx = tid + k * 256;       // < 1536
        int f4 = idx & 15;             // t-quad
        int c = idx >> 4;              // 0..95
        float4 v = make_float4(0.f, 0.f, 0.f, 0.f);
        if (c < NMELS)
            v = *(const float4*)(f + ((size_t)b * NMELS + c) * T_LEN + t0 + f4 * 4);
        lds[(f4 * 4 + 0) * 100 + c] = f2bf(v.x);
        lds[(f4 * 4 + 1) * 100 + c] = f2bf(v.y);
        lds[(f4 * 4 + 2) * 100 + c] = f2bf(v.z);
        lds[(f4 * 4 + 3) * 100 + c] = f2bf(v.w);
    }
    __syncthreads();
    unsigned short* xp = (unsigned short*)xf;
#pragma unroll
    for (int k = 0; k < 6; k++) {
        int idx = tid + k * 256;       // < 1536
        int tl = idx / 24;
        int cq = idx - tl * 24;        // 0..23
        ushort4 o;
        o.x = lds[tl * 100 + cq * 4 + 0];
        o.y = lds[tl * 100 + cq * 4 + 1];
        o.z = lds[tl * 100 + cq * 4 + 2];
        o.w = lds[tl * 100 + cq * 4 + 3];
        *(ushort4*)(xp + ((size_t)b * TP + t0 + tl + 2) * 96 + cq * 4) = o;
    }
}

// ---------- zero the 8 halo t-rows (0,1,4098..4103) of a (b,TP,IC) buffer ----------
template <int IC>
__global__ void zero_rows_kernel(__hip_bfloat16* __restrict__ p) {
    int r = blockIdx.x;            // 0..7
    int b = blockIdx.y;
    int row = (r < 2) ? r : 4096 + r; // 0,1,4098..4103
    ((unsigned short*)p)[((size_t)b * TP + row) * IC + threadIdx.x] = 0;
}

// ---------- zero halo strips of P5 (b,68,120,128) ----------
__global__ __launch_bounds__(256) void zero_p5_halo_kernel(__hip_bfloat16* __restrict__ p) {
    int idx = blockIdx.x * 256 + threadIdx.x; // 32*1760*64
    if (idx >= 32 * 1760 * 64) return;
    int c2 = (idx & 63) * 2;
    int cell = idx >> 6;
    int b = cell / 1760;
    int cl = cell - b * 1760;
    int row, col;
    if (cl < 480) { // rows 0,1,66,67 full width
        int rr = cl / 120;
        row = (rr < 2) ? rr : 64 + rr;
        col = cl - rr * 120;
    } else { // rows 2..65, cols {0,1,102..119}
        int cl2 = cl - 480;
        row = 2 + cl2 / 20;
        int q = cl2 % 20;
        col = (q < 2) ? q : 100 + q;
    }
    *(unsigned int*)((unsigned short*)p + (((size_t)b * WHALO + row) * DHALO + col) * 128 + c2) = 0u;
}

// ---------- conv1d MFMA, LDS-staged + double-buffered (round-10 form, kept) ----------
template <int IC, int CC, bool RELU>
__global__ __launch_bounds__(256, 4) void conv1d_mfma_kernel(const __hip_bfloat16* __restrict__ in,
                                                             const __hip_bfloat16* __restrict__ wf,
                                                             const float* __restrict__ bias,
                                                             __hip_bfloat16* __restrict__ outp) {
    __shared__ short lds[2][4 * 136 * 8]; // 2 x 8704 B
    const int tid = threadIdx.x;
    const int lane = tid & 63;
    const int wid = tid >> 6;
    const int pxg = wid & 1;
    const int cohalf = wid >> 1;
    const int pix0b = blockIdx.x * 128;
    const int b = blockIdx.y;

    const short* inp = (const short*)in;
    const short* wfp = (const short*)wf;

    uint4 v[3];
    auto loadcc = [&](int cc) {
#pragma unroll
        for (int k = 0; k < 3; k++) {
            int c = tid + (k << 8);
            if (c < 528) {
                int jg = c & 3, col = c >> 2; // col 0..131 -> t-row pix0b+col
                v[k] = *(const uint4*)(inp + ((size_t)(b * TP + pix0b + col)) * IC + cc * 32 +
                                       jg * 8);
            }
        }
    };
    auto writecc = [&](int buf) {
#pragma unroll
        for (int k = 0; k < 3; k++) {
            int c = tid + (k << 8);
            if (c < 528) {
                int jg = c & 3, col = c >> 2;
                *(uint4*)&lds[buf][(jg * 136 + col) * 8] = v[k];
            }
        }
    };

    f32x4 acc[4][4];
#pragma unroll
    for (int n = 0; n < 4; n++)
#pragma unroll
        for (int mi = 0; mi < 4; mi++) acc[n][mi] = (f32x4)0.f;

    loadcc(0);
    writecc(0);

#pragma unroll 1
    for (int cc = 0; cc < CC; cc++) {
        __syncthreads(); // publish buf[cc&1]
        if (cc + 1 < CC) loadcc(cc + 1);
        const short* lb = lds[cc & 1];
#pragma unroll 1
        for (int th = 0; th < 5; th++) {
            const short* wptr = wfp + ((cc * 5 + th) * 8 + cohalf * 4) * 512 + lane * 8;
            short8 wfr[4];
#pragma unroll
            for (int mi = 0; mi < 4; mi++) wfr[mi] = *(const short8*)(wptr + mi * 512);

            short8 xfr[4];
#pragma unroll
            for (int n = 0; n < 4; n++)
                xfr[n] = *(const short8*)&lb[((lane >> 4) * 136 + pxg * 64 + th + n * 16 +
                                              (lane & 15)) * 8];

#pragma unroll
            for (int n = 0; n < 4; n++)
#pragma unroll
                for (int mi = 0; mi < 4; mi++)
                    acc[n][mi] =
                        __builtin_amdgcn_mfma_f32_16x16x32_bf16(wfr[mi], xfr[n], acc[n][mi], 0, 0, 0);
        }
        if (cc + 1 < CC) writecc((cc + 1) & 1);
    }

    const int out_base = (b * TP + pix0b + pxg * 64 + 2) * 128;
    unsigned short* outp16 = (unsigned short*)outp;
#pragma unroll
    for (int mi = 0; mi < 4; mi++) {
        const float4 bv = *(const float4*)(bias + cohalf * 64 + mi * 16 + (lane >> 4) * 4);
#pragma unroll
        for (int n = 0; n < 4; n++) {
            const int pix = n * 16 + (lane & 15);
            f32x4 a = acc[n][mi];
            float v0 = a[0] + bv.x, v1 = a[1] + bv.y, v2 = a[2] + bv.z, v3 = a[3] + bv.w;
            if (RELU) {
                v0 = fmaxf(v0, 0.f); v1 = fmaxf(v1, 0.f);
                v2 = fmaxf(v2, 0.f); v3 = fmaxf(v3, 0.f);
            }
            ushort4 o;
            o.x = f2bf(v0); o.y = f2bf(v1); o.z = f2bf(v2); o.w = f2bf(v3);
            *(ushort4*)(outp16 + out_base + pix * 128 + cohalf * 64 + mi * 16 +
                        (lane >> 4) * 4) = o;
        }
    }
}

// ---------- conv2d MFMA, global_load_lds-staged + double-buffered, 512-thr block ----------
// LDS cells [jg(4)][row(8)][col(68)] of 16B, linear -> wave covers 64 contiguous cells.
// Stage(cc) issues async DMA; one barrier per cc drains. No staging VGPRs (no spill).
// GATHER: per-lane global source from word_bounds; out-of-range lanes read zero page.
template <bool GATHER, bool RELU, int OMODE>
__global__ __launch_bounds__(512, 4) void conv2d_lds_kernel(const __hip_bfloat16* __restrict__ in,
                                                            const int* __restrict__ wb,
                                                            const __hip_bfloat16* __restrict__ wf,
                                                            const float* __restrict__ bias,
                                                            const __hip_bfloat16* __restrict__ zp,
                                                            __hip_bfloat16* __restrict__ outp) {
    __shared__ short lds[2][4 * 8 * 68 * 8]; // 2 x 34,816 B
    __shared__ int2 s_sd[8];
    const int tid = threadIdx.x;
    const int lane = tid & 63;
    const int wid = tid >> 6;
    const int wrow = wid & 3;
    const int cohalf = wid >> 2;
    const int w0 = (blockIdx.x & 15) * 4;
    const int dtile = blockIdx.x >> 4;
    const int D0 = dtile * 64;
    const int ntlim = dtile ? 3 : 4;
    const int b = blockIdx.y;
    const int w = w0 + wrow;

    if (GATHER && tid < 8) {
        int wg = w0 + tid - 2;
        int s = 0, du = 0;
        if (wg >= 0 && wg < 64) {
            s = wb[(b * 64 + wg) * 2];
            du = wb[(b * 64 + wg) * 2 + 1] - s;
            if (du > D_MAX) du = D_MAX; // reference masks d < MAX_DUR
        }
        s_sd[tid] = make_int2(s, du);
    }
    __syncthreads(); // s_sd visible before prologue staging

    const short* inp = (const short*)in;
    const short* wfp = (const short*)wf;

    // stage all 2176 cells (both d-tiles; tail tile's cols 52..67 are staged-but-unread)
    auto stage = [&](int cc, int buf) {
        short* lbase = &lds[buf][0];
#pragma unroll
        for (int it = 0; it < 5; it++) {
            int cbase = (it * 8 + wid) * 64;
            if (cbase < 2176) {
                int cell = cbase + lane;
                int jg = cell / 544; // 8*68
                int rem = cell - jg * 544;
                int row = rem / 68;
                int col = rem - row * 68;
                const short* g;
                if (GATHER) {
                    int d = D0 + col - 2;
                    int2 sd = s_sd[row];
                    if ((unsigned)d < (unsigned)sd.y)
                        g = inp + ((size_t)(b * TP + 2 + sd.x + d)) * 128 + cc * 32 + jg * 8;
                    else
                        g = (const short*)zp;
                } else {
                    g = inp + ((size_t)((b * WHALO + w0 + row) * DHALO + D0 + col)) * 128 +
                        cc * 32 + jg * 8;
                }
                gload16(g, lbase + (size_t)cbase * 8);
            }
        }
    };

    f32x4 acc[4][4];
#pragma unroll
    for (int n = 0; n < 4; n++)
#pragma unroll
        for (int mi = 0; mi < 4; mi++) acc[n][mi] = (f32x4)0.f;

    stage(0, 0);

#pragma unroll 1
    for (int cc = 0; cc < 4; cc++) {
        __syncthreads(); // drain in-flight DMA -> buf[cc&1] ready
        if (cc < 3) stage(cc + 1, (cc + 1) & 1); // async, overlaps compute below
        const short* lbuf = lds[cc & 1];
#pragma unroll 1
        for (int th = 0; th < 5; th++) {
#pragma unroll
            for (int tw = 0; tw < 5; tw++) {
                const int tap = th * 5 + tw;
                const short* wptr = wfp + ((cc * 25 + tap) * 8 + cohalf * 4) * 512 + lane * 8;
                short8 wfr[4];
#pragma unroll
                for (int mi = 0; mi < 4; mi++) wfr[mi] = *(const short8*)(wptr + mi * 512);

                short8 xfr[4];
#pragma unroll
                for (int n = 0; n < 4; n++)
                    if (n < ntlim)
                        xfr[n] = *(const short8*)&lbuf[(((lane >> 4) * 8 + wrow + th) * 68 +
                                                        (tw + n * 16 + (lane & 15))) * 8];

#pragma unroll
                for (int n = 0; n < 4; n++)
                    if (n < ntlim)
#pragma unroll
                        for (int mi = 0; mi < 4; mi++)
                            acc[n][mi] = __builtin_amdgcn_mfma_f32_16x16x32_bf16(
                                wfr[mi], xfr[n], acc[n][mi], 0, 0, 0);
            }
        }
    }

    int out_base;
    if (OMODE == 1)
        out_base = ((b * WHALO + w + 2) * DHALO + D0 + 2) * 128;
    else
        out_base = ((b * 64 + w) * 100 + D0) * 128;

    unsigned short* outp16 = (unsigned short*)outp;
#pragma unroll
    for (int mi = 0; mi < 4; mi++) {
        const float4 bv = *(const float4*)(bias + cohalf * 64 + mi * 16 + (lane >> 4) * 4);
#pragma unroll
        for (int n = 0; n < 4; n++) {
            const int pix = n * 16 + (lane & 15);
            if (D0 + pix >= 100) continue; // tail overhang (also skips n=3 when ntlim=3)
            f32x4 a = acc[n][mi];
            float v0 = a[0] + bv.x, v1 = a[1] + bv.y, v2 = a[2] + bv.z, v3 = a[3] + bv.w;
            if (RELU) {
                v0 = fmaxf(v0, 0.f); v1 = fmaxf(v1, 0.f);
                v2 = fmaxf(v2, 0.f); v3 = fmaxf(v3, 0.f);
            }
            ushort4 o;
            o.x = f2bf(v0); o.y = f2bf(v1); o.z = f2bf(v2); o.w = f2bf(v3);
            *(ushort4*)(outp16 + out_base + pix * 128 + cohalf * 64 + mi * 16 +
                        (lane >> 4) * 4) = o;
        }
    }
}

// ---------- einsum over d + relu: Q (b,64,100,128) bf16 -> xe (b,128,64) fp32 ----------
__global__ __launch_bounds__(128) void einsum_kernel(const __hip_bfloat16* __restrict__ Q,
                                                     const float* __restrict__ lw,
                                                     const float* __restrict__ lb,
                                                     float* __restrict__ xe) {
    const int w = blockIdx.x;
    const int b = blockIdx.y;
    const int c = threadIdx.x;
    const unsigned short* qp = (const unsigned short*)Q + ((b * 64 + w) * 100) * 128 + c;
    float acc = 0.f;
#pragma unroll 4
    for (int d = 0; d < D_MAX; d++) {
        unsigned int u = (unsigned int)qp[d * 128] << 16;
        acc += *reinterpret_cast<float*>(&u) * lw[d];
    }
    xe[(b * 128 + c) * 64 + w] = fmaxf(acc + lb[0], 0.f);
}

// ---------- final conv: xe (b,128,64) fp32 -> out (b,64); only kw==2 column of w6 ----------
__global__ void conv6_kernel(const float* __restrict__ xe, const float* __restrict__ w6,
                             const float* __restrict__ b6, float* __restrict__ out) {
    int b = blockIdx.x;
    int w = threadIdx.x; // 64
    float acc = b6[0];
#pragma unroll 1
    for (int ci = 0; ci < 128; ci++) {
        const float* xr = xe + (b * 128 + ci) * 64;
#pragma unroll
        for (int kh = 0; kh < 5; kh++) {
            int ww = w + kh - 2;
            if ((unsigned)ww < 64u) acc += xr[ww] * w6[ci * 25 + kh * 5 + 2];
        }
    }
    out[b * 64 + w] = acc;
}

extern "C" void kernel_launch(void* const* d_in, const int* in_sizes, int n_in,
                              void* d_out, int out_size, void* d_ws, size_t ws_size,
                              hipStream_t stream) {
    const float* features = (const float*)d_in[0];
    const int* wbnd = (const int*)d_in[1];
    const float* w1 = (const float*)d_in[2];
    const float* b1 = (const float*)d_in[3];
    const float* w2 = (const float*)d_in[4];
    const float* b2 = (const float*)d_in[5];
    const float* w3 = (const float*)d_in[6];
    const float* b3 = (const float*)d_in[7];
    const float* w4 = (const float*)d_in[8];
    const float* b4 = (const float*)d_in[9];
    const float* w5 = (const float*)d_in[10];
    const float* b5 = (const float*)d_in[11];
    const float* lw = (const float*)d_in[12];
    const float* lb = (const float*)d_in[13];
    const float* w6 = (const float*)d_in[14];
    const float* b6 = (const float*)d_in[15];
    float* out = (float*)d_out;

    char* base = (char*)d_ws;
    size_t off = 0;
    auto alloc = [&](size_t bytes) -> char* {
        char* p = base + off;
        off += (bytes + 255) & ~(size_t)255;
        return p;
    };

    __hip_bfloat16* ZP = (__hip_bfloat16*)alloc(256); // zero page for gather OOB lanes
    __hip_bfloat16* XF = (__hip_bfloat16*)alloc((size_t)BATCH * TP * 96 * 2);
    __hip_bfloat16* Y1 = (__hip_bfloat16*)alloc((size_t)BATCH * TP * 128 * 2);
    __hip_bfloat16* Y2 = (__hip_bfloat16*)alloc((size_t)BATCH * TP * 128 * 2);
    __hip_bfloat16* P5 = (__hip_bfloat16*)alloc((size_t)BATCH * WHALO * DHALO * 128 * 2);
    __hip_bfloat16* Q  = (__hip_bfloat16*)alloc((size_t)BATCH * 64 * 100 * 128 * 2);
    float* XE = (float*)alloc((size_t)BATCH * 128 * 64 * 4);
    __hip_bfloat16* WF1 = (__hip_bfloat16*)alloc((size_t)3 * 5 * 8 * 512 * 2);
    __hip_bfloat16* WF2 = (__hip_bfloat16*)alloc((size_t)4 * 5 * 8 * 512 * 2);
    __hip_bfloat16* WF3 = (__hip_bfloat16*)alloc((size_t)4 * 5 * 8 * 512 * 2);
    __hip_bfloat16* WF4 = (__hip_bfloat16*)alloc((size_t)4 * 25 * 8 * 512 * 2);
    __hip_bfloat16* WF5 = (__hip_bfloat16*)alloc((size_t)4 * 25 * 8 * 512 * 2);

    hipMemsetAsync(ZP, 0, 256, stream);

    // zero halo rows/strips (interiors fully overwritten each call)
    zero_rows_kernel<96><<<dim3(8, 32), 96, 0, stream>>>(XF);
    zero_rows_kernel<128><<<dim3(8, 32), 128, 0, stream>>>(Y1);
    zero_rows_kernel<128><<<dim3(8, 32), 128, 0, stream>>>(Y2);
    zero_p5_halo_kernel<<<14080, 256, 0, stream>>>(P5);

    pack_w_kernel<80, 3, 5><<<240, 256, 0, stream>>>(w1, WF1);
    pack_w_kernel<128, 4, 5><<<320, 256, 0, stream>>>(w2, WF2);
    pack_w_kernel<128, 4, 5><<<320, 256, 0, stream>>>(w3, WF3);
    pack_w_kernel<128, 4, 25><<<1600, 256, 0, stream>>>(w4, WF4);
    pack_w_kernel<128, 4, 25><<<1600, 256, 0, stream>>>(w5, WF5);

    cast_feat_kernel<<<dim3(64, 32), 256, 0, stream>>>(features, XF);

    // conv1d stack: 256-thr blocks, LDS dbuf; block = 128 px
    conv1d_mfma_kernel<96, 3, true><<<dim3(32, 32), 256, 0, stream>>>(XF, WF1, b1, Y1);
    conv1d_mfma_kernel<128, 4, true><<<dim3(32, 32), 256, 0, stream>>>(Y1, WF2, b2, Y2);
    conv1d_mfma_kernel<128, 4, false><<<dim3(32, 32), 256, 0, stream>>>(Y2, WF3, b3, Y1); // E := Y1

    // conv4: gather fused into DMA staging; E -> P5 (halo plane)
    conv2d_lds_kernel<true, true, 1><<<dim3(32, 32), 512, 0, stream>>>(Y1, wbnd, WF4, b4, ZP, P5);

    // conv5: P5 -> Q (compact)
    conv2d_lds_kernel<false, true, 2><<<dim3(32, 32), 512, 0, stream>>>(P5, wbnd, WF5, b5, ZP, Q);

    einsum_kernel<<<dim3(64, 32), 128, 0, stream>>>(Q, lw, lb, XE);
    conv6_kernel<<<32, 64, 0, stream>>>(XE, w6, b6, out);
}

// Round 13
// 504.202 us; speedup vs baseline: 2.4474x; 1.0741x over previous
//
#include <hip/hip_runtime.h>
#include <hip/hip_bf16.h>
#include <cstdint>
#include <cstddef>

#define T_LEN 4096
#define TP 4104      // padded t rows: pixel t lives at row t+2; rows 0,1 and 4098..4103 are zero
#define BATCH 32
#define NMELS 80
#define HID 128
#define W_WORDS 64
#define D_MAX 100
#define WHALO 68
#define DHALO 120    // pixel d at halo row d+2; rows 0,1 and 102..119 zero

typedef __attribute__((ext_vector_type(4))) float f32x4;
typedef __attribute__((ext_vector_type(8))) short short8;

static __device__ __forceinline__ unsigned short f2bf(float f) {
    __hip_bfloat16 h = __float2bfloat16(f);
    return *reinterpret_cast<unsigned short*>(&h);
}

// async global->LDS DMA, 16B per lane; dest = wave-uniform base + lane*16
typedef const __attribute__((address_space(1))) unsigned int* as1_u32p;
typedef __attribute__((address_space(3))) unsigned int* as3_u32p;
static __device__ __forceinline__ void gload16(const void* g, void* l) {
    __builtin_amdgcn_global_load_lds((as1_u32p)(uintptr_t)g, (as3_u32p)(uintptr_t)l, 16, 0, 0);
}

// ---------- pack weights into MFMA A-fragment order ----------
// wf[((cc*TAPS + tap)*8 + mi)*512 + lane*8 + j] = w[co][ci][tap], co=mi*16+(lane&15), ci=cc*32+(lane>>4)*8+j
template <int CIN, int CC, int TAPS>
__global__ __launch_bounds__(256) void pack_w_kernel(const float* __restrict__ w,
                                                     __hip_bfloat16* __restrict__ wf) {
    int idx = blockIdx.x * 256 + threadIdx.x; // CC*TAPS*8*64*8
    int r = idx;
    int j = r & 7; r >>= 3;
    int lane = r & 63; r >>= 6;
    int mi = r & 7; r >>= 3;
    int tap = r % TAPS;
    int cc = r / TAPS;
    if (cc >= CC) return;
    int co = mi * 16 + (lane & 15);
    int ci = cc * 32 + (lane >> 4) * 8 + j;
    float v = (ci < CIN) ? w[(co * CIN + ci) * TAPS + tap] : 0.f;
    wf[idx] = __float2bfloat16(v);
}

// ---------- cast features: tiled LDS transpose (b,80,t) fp32 -> XF (b,TP,96) bf16 ----------
__global__ __launch_bounds__(256) void cast_feat_kernel(const float* __restrict__ f,
                                                        __hip_bfloat16* __restrict__ xf) {
    __shared__ unsigned short lds[64 * 100]; // [t_local][c] c-padded to 100
    const int tid = threadIdx.x;
    const int t0 = blockIdx.x * 64;
    const int b = blockIdx.y;

#pragma unroll
    for (int k = 0; k < 6; k++) {
        int idx = tid + k * 256;       // < 1536
        int f4 = idx & 15;             // t-quad
        int c = idx >> 4;              // 0..95
        float4 v = make_float4(0.f, 0.f, 0.f, 0.f);
        if (c < NMELS)
            v = *(const float4*)(f + ((size_t)b * NMELS + c) * T_LEN + t0 + f4 * 4);
        lds[(f4 * 4 + 0) * 100 + c] = f2bf(v.x);
        lds[(f4 * 4 + 1) * 100 + c] = f2bf(v.y);
        lds[(f4 * 4 + 2) * 100 + c] = f2bf(v.z);
        lds[(f4 * 4 + 3) * 100 + c] = f2bf(v.w);
    }
    __syncthreads();
    unsigned short* xp = (unsigned short*)xf;
#pragma unroll
    for (int k = 0; k < 6; k++) {
        int idx = tid + k * 256;       // < 1536
        int tl = idx / 24;
        int cq = idx - tl * 24;        // 0..23
        ushort4 o;
        o.x = lds[tl * 100 + cq * 4 + 0];
        o.y = lds[tl * 100 + cq * 4 + 1];
        o.z = lds[tl * 100 + cq * 4 + 2];
        o.w = lds[tl * 100 + cq * 4 + 3];
        *(ushort4*)(xp + ((size_t)b * TP + t0 + tl + 2) * 96 + cq * 4) = o;
    }
}

// ---------- zero the 8 halo t-rows (0,1,4098..4103) of a (b,TP,IC) buffer ----------
template <int IC>
__global__ void zero_rows_kernel(__hip_bfloat16* __restrict__ p) {
    int r = blockIdx.x;            // 0..7
    int b = blockIdx.y;
    int row = (r < 2) ? r : 4096 + r; // 0,1,4098..4103
    ((unsigned short*)p)[((size_t)b * TP + row) * IC + threadIdx.x] = 0;
}

// ---------- zero halo strips of P5 (b,68,120,128) ----------
__global__ __launch_bounds__(256) void zero_p5_halo_kernel(__hip_bfloat16* __restrict__ p) {
    int idx = blockIdx.x * 256 + threadIdx.x; // 32*1760*64
    if (idx >= 32 * 1760 * 64) return;
    int c2 = (idx & 63) * 2;
    int cell = idx >> 6;
    int b = cell / 1760;
    int cl = cell - b * 1760;
    int row, col;
    if (cl < 480) { // rows 0,1,66,67 full width
        int rr = cl / 120;
        row = (rr < 2) ? rr : 64 + rr;
        col = cl - rr * 120;
    } else { // rows 2..65, cols {0,1,102..119}
        int cl2 = cl - 480;
        row = 2 + cl2 / 20;
        int q = cl2 % 20;
        col = (q < 2) ? q : 100 + q;
    }
    *(unsigned int*)((unsigned short*)p + (((size_t)b * WHALO + row) * DHALO + col) * 128 + c2) = 0u;
}

// ---------- conv1d MFMA, gload_lds-staged + double-buffered ----------
// 256-thr block = 2 px-groups x 2 co-halves; block covers 128 px (+4 halo).
// LDS cells [jg(4)][col(136)] of 16B (= 544 used cells) PADDED to 576 cells/buffer:
// DMA staging moves whole-wave 64-cell transfers (9x64=576) and the dest lane offset
// cannot be masked — tail-wave lanes land in the padding, not the next buffer.
template <int IC, int CC, bool RELU>
__global__ __launch_bounds__(256, 4) void conv1d_mfma_kernel(const __hip_bfloat16* __restrict__ in,
                                                             const __hip_bfloat16* __restrict__ wf,
                                                             const float* __restrict__ bias,
                                                             __hip_bfloat16* __restrict__ outp) {
    __shared__ short lds[2][576 * 8]; // 2 x 9216 B (544 used + 32 pad cells)
    const int tid = threadIdx.x;
    const int lane = tid & 63;
    const int wid = tid >> 6;
    const int pxg = wid & 1;
    const int cohalf = wid >> 1;
    const int pix0b = blockIdx.x * 128;
    const int b = blockIdx.y;

    const short* inp = (const short*)in;
    const short* wfp = (const short*)wf;

    auto stage = [&](int cc, int buf) {
        short* lbase = &lds[buf][0];
#pragma unroll
        for (int it = 0; it < 3; it++) {
            int cbase = (it * 4 + wid) * 64;
            if (cbase < 544) {
                int cell = cbase + lane;
                int jg = cell / 136;       // cells >= 544 (pad): jg=4 -> junk src, in-bounds
                int col = cell - jg * 136; // cols 132..135 staged-but-unread (in-bounds)
                if (jg > 3) { jg = 3; col = 135; } // clamp pad-lane SOURCE (dest is pad cell)
                const short* g = inp + ((size_t)(b * TP + pix0b + col)) * IC + cc * 32 + jg * 8;
                gload16(g, lbase + (size_t)cbase * 8);
            }
        }
    };

    f32x4 acc[4][4];
#pragma unroll
    for (int n = 0; n < 4; n++)
#pragma unroll
        for (int mi = 0; mi < 4; mi++) acc[n][mi] = (f32x4)0.f;

    stage(0, 0);

#pragma unroll 1
    for (int cc = 0; cc < CC; cc++) {
        __syncthreads(); // drain stage(cc) DMA; prev readers done
        if (cc + 1 < CC) stage(cc + 1, (cc + 1) & 1);
        const short* lb = lds[cc & 1];
#pragma unroll 1
        for (int th = 0; th < 5; th++) {
            const short* wptr = wfp + ((cc * 5 + th) * 8 + cohalf * 4) * 512 + lane * 8;
            short8 wfr[4];
#pragma unroll
            for (int mi = 0; mi < 4; mi++) wfr[mi] = *(const short8*)(wptr + mi * 512);

            short8 xfr[4];
#pragma unroll
            for (int n = 0; n < 4; n++)
                xfr[n] = *(const short8*)&lb[((lane >> 4) * 136 + pxg * 64 + th + n * 16 +
                                              (lane & 15)) * 8];

#pragma unroll
            for (int n = 0; n < 4; n++)
#pragma unroll
                for (int mi = 0; mi < 4; mi++)
                    acc[n][mi] =
                        __builtin_amdgcn_mfma_f32_16x16x32_bf16(wfr[mi], xfr[n], acc[n][mi], 0, 0, 0);
        }
    }

    const int out_base = (b * TP + pix0b + pxg * 64 + 2) * 128;
    unsigned short* outp16 = (unsigned short*)outp;
#pragma unroll
    for (int mi = 0; mi < 4; mi++) {
        const float4 bv = *(const float4*)(bias + cohalf * 64 + mi * 16 + (lane >> 4) * 4);
#pragma unroll
        for (int n = 0; n < 4; n++) {
            const int pix = n * 16 + (lane & 15);
            f32x4 a = acc[n][mi];
            float v0 = a[0] + bv.x, v1 = a[1] + bv.y, v2 = a[2] + bv.z, v3 = a[3] + bv.w;
            if (RELU) {
                v0 = fmaxf(v0, 0.f); v1 = fmaxf(v1, 0.f);
                v2 = fmaxf(v2, 0.f); v3 = fmaxf(v3, 0.f);
            }
            ushort4 o;
            o.x = f2bf(v0); o.y = f2bf(v1); o.z = f2bf(v2); o.w = f2bf(v3);
            *(ushort4*)(outp16 + out_base + pix * 128 + cohalf * 64 + mi * 16 +
                        (lane >> 4) * 4) = o;
        }
    }
}

// ---------- conv2d MFMA, gload_lds-staged SINGLE-buffer (2-barrier), 512-thr block ----------
// LDS cells [jg(4)][row(8)][col(68)] of 16B, linear; 2176 cells = 34 whole-wave transfers
// (exact, no overflow). 34.8 KB -> 4 blocks/CU (8 waves/SIMD).
// GATHER: per-lane global source from word_bounds; OOB lanes read zero page.
// OMODE 1: store bf16 halo plane. OMODE 2: FUSED einsum -> fp32 partials xep[b,co,w,2].
template <bool GATHER, bool RELU, int OMODE>
__global__ __launch_bounds__(512, 4) void conv2d_lds_kernel(const __hip_bfloat16* __restrict__ in,
                                                            const int* __restrict__ wb,
                                                            const __hip_bfloat16* __restrict__ wf,
                                                            const float* __restrict__ bias,
                                                            const __hip_bfloat16* __restrict__ zp,
                                                            const float* __restrict__ lw,
                                                            float* __restrict__ xep,
                                                            __hip_bfloat16* __restrict__ outp) {
    __shared__ short lds[4 * 8 * 68 * 8]; // 34,816 B; 2176 cells = 34*64 exact
    __shared__ int2 s_sd[8];
    const int tid = threadIdx.x;
    const int lane = tid & 63;
    const int wid = tid >> 6;
    const int wrow = wid & 3;
    const int cohalf = wid >> 2;
    const int w0 = (blockIdx.x & 15) * 4;
    const int dtile = blockIdx.x >> 4;
    const int D0 = dtile * 64;
    const int ntlim = dtile ? 3 : 4;
    const int b = blockIdx.y;
    const int w = w0 + wrow;

    if (GATHER && tid < 8) {
        int wg = w0 + tid - 2;
        int s = 0, du = 0;
        if (wg >= 0 && wg < 64) {
            s = wb[(b * 64 + wg) * 2];
            du = wb[(b * 64 + wg) * 2 + 1] - s;
            if (du > D_MAX) du = D_MAX; // reference masks d < MAX_DUR
        }
        s_sd[tid] = make_int2(s, du);
    }
    __syncthreads(); // s_sd visible before staging

    const short* inp = (const short*)in;
    const short* wfp = (const short*)wf;

    auto stage = [&](int cc) {
#pragma unroll
        for (int it = 0; it < 5; it++) {
            int cbase = (it * 8 + wid) * 64;
            if (cbase < 2176) {
                int cell = cbase + lane;
                int jg = cell / 544; // 8*68
                int rem = cell - jg * 544;
                int row = rem / 68;
                int col = rem - row * 68;
                const short* g;
                if (GATHER) {
                    int d = D0 + col - 2;
                    int2 sd = s_sd[row];
                    if ((unsigned)d < (unsigned)sd.y)
                        g = inp + ((size_t)(b * TP + 2 + sd.x + d)) * 128 + cc * 32 + jg * 8;
                    else
                        g = (const short*)zp;
                } else {
                    g = inp + ((size_t)((b * WHALO + w0 + row) * DHALO + D0 + col)) * 128 +
                        cc * 32 + jg * 8;
                }
                gload16(g, &lds[0] + (size_t)cbase * 8);
            }
        }
    };

    f32x4 acc[4][4];
#pragma unroll
    for (int n = 0; n < 4; n++)
#pragma unroll
        for (int mi = 0; mi < 4; mi++) acc[n][mi] = (f32x4)0.f;

#pragma unroll 1
    for (int cc = 0; cc < 4; cc++) {
        if (cc) __syncthreads(); // readers of lds done
        stage(cc);               // async DMA issue
        __syncthreads();         // drain -> lds ready
#pragma unroll 1
        for (int th = 0; th < 5; th++) {
#pragma unroll
            for (int tw = 0; tw < 5; tw++) {
                const int tap = th * 5 + tw;
                const short* wptr = wfp + ((cc * 25 + tap) * 8 + cohalf * 4) * 512 + lane * 8;
                short8 wfr[4];
#pragma unroll
                for (int mi = 0; mi < 4; mi++) wfr[mi] = *(const short8*)(wptr + mi * 512);

                short8 xfr[4];
#pragma unroll
                for (int n = 0; n < 4; n++)
                    if (n < ntlim)
                        xfr[n] = *(const short8*)&lds[(((lane >> 4) * 8 + wrow + th) * 68 +
                                                       (tw + n * 16 + (lane & 15))) * 8];

#pragma unroll
                for (int n = 0; n < 4; n++)
                    if (n < ntlim)
#pragma unroll
                        for (int mi = 0; mi < 4; mi++)
                            acc[n][mi] = __builtin_amdgcn_mfma_f32_16x16x32_bf16(
                                wfr[mi], xfr[n], acc[n][mi], 0, 0, 0);
            }
        }
    }

    if (OMODE == 1) {
        const int out_base = ((b * WHALO + w + 2) * DHALO + D0 + 2) * 128;
        unsigned short* outp16 = (unsigned short*)outp;
#pragma unroll
        for (int mi = 0; mi < 4; mi++) {
            const float4 bv = *(const float4*)(bias + cohalf * 64 + mi * 16 + (lane >> 4) * 4);
#pragma unroll
            for (int n = 0; n < 4; n++) {
                const int pix = n * 16 + (lane & 15);
                if (D0 + pix >= 100) continue;
                f32x4 a = acc[n][mi];
                float v0 = a[0] + bv.x, v1 = a[1] + bv.y, v2 = a[2] + bv.z, v3 = a[3] + bv.w;
                if (RELU) {
                    v0 = fmaxf(v0, 0.f); v1 = fmaxf(v1, 0.f);
                    v2 = fmaxf(v2, 0.f); v3 = fmaxf(v3, 0.f);
                }
                ushort4 o;
                o.x = f2bf(v0); o.y = f2bf(v1); o.z = f2bf(v2); o.w = f2bf(v3);
                *(ushort4*)(outp16 + out_base + pix * 128 + cohalf * 64 + mi * 16 +
                            (lane >> 4) * 4) = o;
            }
        }
    } else {
        // fused einsum: e[mi][j] = sum_d relu(acc+bias) * lw[d] over this block's d-range
        float e[4][4];
#pragma unroll
        for (int mi = 0; mi < 4; mi++)
#pragma unroll
            for (int j = 0; j < 4; j++) e[mi][j] = 0.f;

#pragma unroll
        for (int mi = 0; mi < 4; mi++) {
            const float4 bv = *(const float4*)(bias + cohalf * 64 + mi * 16 + (lane >> 4) * 4);
#pragma unroll
            for (int n = 0; n < 4; n++) {
                const int pix = n * 16 + (lane & 15);
                if (D0 + pix >= 100) continue;
                const float lwv = lw[D0 + pix];
                f32x4 a = acc[n][mi];
                float v0 = fmaxf(a[0] + bv.x, 0.f);
                float v1 = fmaxf(a[1] + bv.y, 0.f);
                float v2 = fmaxf(a[2] + bv.z, 0.f);
                float v3 = fmaxf(a[3] + bv.w, 0.f);
                e[mi][0] += v0 * lwv;
                e[mi][1] += v1 * lwv;
                e[mi][2] += v2 * lwv;
                e[mi][3] += v3 * lwv;
            }
        }
        // butterfly reduce across the 16 pixel-lanes of each quad-group
#pragma unroll
        for (int mi = 0; mi < 4; mi++)
#pragma unroll
            for (int j = 0; j < 4; j++) {
                float v = e[mi][j];
                v += __shfl_xor(v, 1);
                v += __shfl_xor(v, 2);
                v += __shfl_xor(v, 4);
                v += __shfl_xor(v, 8);
                e[mi][j] = v;
            }
        if ((lane & 15) == 0) {
#pragma unroll
            for (int mi = 0; mi < 4; mi++)
#pragma unroll
                for (int j = 0; j < 4; j++) {
                    int co = cohalf * 64 + mi * 16 + (lane >> 4) * 4 + j;
                    xep[(((size_t)b * 128 + co) * 64 + w) * 2 + dtile] = e[mi][j];
                }
        }
    }
}

// ---------- final conv: XEp partials (b,128,64,2) + lb -> relu -> conv over w -> out (b,64) ----------
__global__ void conv6_kernel(const float* __restrict__ xep, const float* __restrict__ lb,
                             const float* __restrict__ w6, const float* __restrict__ b6,
                             float* __restrict__ out) {
    int b = blockIdx.x;
    int w = threadIdx.x; // 64
    float acc = b6[0];
    const float lb0 = lb[0];
#pragma unroll 1
    for (int ci = 0; ci < 128; ci++) {
        const float* xr = xep + (((size_t)b * 128 + ci) * 64) * 2;
#pragma unroll
        for (int kh = 0; kh < 5; kh++) {
            int ww = w + kh - 2;
            if ((unsigned)ww < 64u) {
                float x = fmaxf(xr[ww * 2] + xr[ww * 2 + 1] + lb0, 0.f);
                acc += x * w6[ci * 25 + kh * 5 + 2];
            }
        }
    }
    out[b * 64 + w] = acc;
}

extern "C" void kernel_launch(void* const* d_in, const int* in_sizes, int n_in,
                              void* d_out, int out_size, void* d_ws, size_t ws_size,
                              hipStream_t stream) {
    const float* features = (const float*)d_in[0];
    const int* wbnd = (const int*)d_in[1];
    const float* w1 = (const float*)d_in[2];
    const float* b1 = (const float*)d_in[3];
    const float* w2 = (const float*)d_in[4];
    const float* b2 = (const float*)d_in[5];
    const float* w3 = (const float*)d_in[6];
    const float* b3 = (const float*)d_in[7];
    const float* w4 = (const float*)d_in[8];
    const float* b4 = (const float*)d_in[9];
    const float* w5 = (const float*)d_in[10];
    const float* b5 = (const float*)d_in[11];
    const float* lw = (const float*)d_in[12];
    const float* lb = (const float*)d_in[13];
    const float* w6 = (const float*)d_in[14];
    const float* b6 = (const float*)d_in[15];
    float* out = (float*)d_out;

    char* base = (char*)d_ws;
    size_t off = 0;
    auto alloc = [&](size_t bytes) -> char* {
        char* p = base + off;
        off += (bytes + 255) & ~(size_t)255;
        return p;
    };

    __hip_bfloat16* ZP = (__hip_bfloat16*)alloc(256); // zero page for gather OOB lanes
    __hip_bfloat16* XF = (__hip_bfloat16*)alloc((size_t)BATCH * TP * 96 * 2);
    __hip_bfloat16* Y1 = (__hip_bfloat16*)alloc((size_t)BATCH * TP * 128 * 2);
    __hip_bfloat16* Y2 = (__hip_bfloat16*)alloc((size_t)BATCH * TP * 128 * 2);
    __hip_bfloat16* P5 = (__hip_bfloat16*)alloc((size_t)BATCH * WHALO * DHALO * 128 * 2);
    float* XEp = (float*)alloc((size_t)BATCH * 128 * 64 * 2 * 4); // einsum partials per d-tile
    __hip_bfloat16* WF1 = (__hip_bfloat16*)alloc((size_t)3 * 5 * 8 * 512 * 2);
    __hip_bfloat16* WF2 = (__hip_bfloat16*)alloc((size_t)4 * 5 * 8 * 512 * 2);
    __hip_bfloat16* WF3 = (__hip_bfloat16*)alloc((size_t)4 * 5 * 8 * 512 * 2);
    __hip_bfloat16* WF4 = (__hip_bfloat16*)alloc((size_t)4 * 25 * 8 * 512 * 2);
    __hip_bfloat16* WF5 = (__hip_bfloat16*)alloc((size_t)4 * 25 * 8 * 512 * 2);

    hipMemsetAsync(ZP, 0, 256, stream);

    // zero halo rows/strips (interiors fully overwritten each call)
    zero_rows_kernel<96><<<dim3(8, 32), 96, 0, stream>>>(XF);
    zero_rows_kernel<128><<<dim3(8, 32), 128, 0, stream>>>(Y1);
    zero_rows_kernel<128><<<dim3(8, 32), 128, 0, stream>>>(Y2);
    zero_p5_halo_kernel<<<14080, 256, 0, stream>>>(P5);

    pack_w_kernel<80, 3, 5><<<240, 256, 0, stream>>>(w1, WF1);
    pack_w_kernel<128, 4, 5><<<320, 256, 0, stream>>>(w2, WF2);
    pack_w_kernel<128, 4, 5><<<320, 256, 0, stream>>>(w3, WF3);
    pack_w_kernel<128, 4, 25><<<1600, 256, 0, stream>>>(w4, WF4);
    pack_w_kernel<128, 4, 25><<<1600, 256, 0, stream>>>(w5, WF5);

    cast_feat_kernel<<<dim3(64, 32), 256, 0, stream>>>(features, XF);

    // conv1d stack: 256-thr blocks, gload_lds dbuf; block = 128 px
    conv1d_mfma_kernel<96, 3, true><<<dim3(32, 32), 256, 0, stream>>>(XF, WF1, b1, Y1);
    conv1d_mfma_kernel<128, 4, true><<<dim3(32, 32), 256, 0, stream>>>(Y1, WF2, b2, Y2);
    conv1d_mfma_kernel<128, 4, false><<<dim3(32, 32), 256, 0, stream>>>(Y2, WF3, b3, Y1); // E := Y1

    // conv4: gather fused into DMA staging; E -> P5 (halo plane)
    conv2d_lds_kernel<true, true, 1><<<dim3(32, 32), 512, 0, stream>>>(Y1, wbnd, WF4, b4, ZP,
                                                                       nullptr, nullptr, P5);

    // conv5 + fused einsum: P5 -> XEp fp32 partials (no Q buffer)
    conv2d_lds_kernel<false, true, 2><<<dim3(32, 32), 512, 0, stream>>>(P5, wbnd, WF5, b5, ZP,
                                                                        lw, XEp, nullptr);

    conv6_kernel<<<32, 64, 0, stream>>>(XEp, lb, w6, b6, out);
}

// Round 15
// 483.004 us; speedup vs baseline: 2.5548x; 1.0439x over previous
//
#include <hip/hip_runtime.h>
#include <hip/hip_bf16.h>
#include <cstdint>
#include <cstddef>

#define T_LEN 4096
#define TP 4104      // emb rows: pixel t at row t+2; rows 0,1 and 4098..4103 zero
#define TPX 4120     // XF rows: pixel t at row t+10; rows 0..9 and 4106..4119 zero
#define BATCH 32
#define NMELS 80
#define HID 128
#define W_WORDS 64
#define D_MAX 100
#define WHALO 68
#define DHALO 120

typedef __attribute__((ext_vector_type(4))) float f32x4;
typedef __attribute__((ext_vector_type(8))) short short8;

static __device__ __forceinline__ unsigned short f2bf(float f) {
    __hip_bfloat16 h = __float2bfloat16(f);
    return *reinterpret_cast<unsigned short*>(&h);
}

// async global->LDS DMA, 16B per lane; dest = wave-uniform base + lane*16
typedef const __attribute__((address_space(1))) unsigned int* as1_u32p;
typedef __attribute__((address_space(3))) unsigned int* as3_u32p;
static __device__ __forceinline__ void gload16(const void* g, void* l) {
    __builtin_amdgcn_global_load_lds((as1_u32p)(uintptr_t)g, (as3_u32p)(uintptr_t)l, 16, 0, 0);
}

// ---------- pack weights into MFMA A-fragment order ----------
template <int CIN, int CC, int TAPS>
__global__ __launch_bounds__(256) void pack_w_kernel(const float* __restrict__ w,
                                                     __hip_bfloat16* __restrict__ wf) {
    int idx = blockIdx.x * 256 + threadIdx.x;
    int r = idx;
    int j = r & 7; r >>= 3;
    int lane = r & 63; r >>= 6;
    int mi = r & 7; r >>= 3;
    int tap = r % TAPS;
    int cc = r / TAPS;
    if (cc >= CC) return;
    int co = mi * 16 + (lane & 15);
    int ci = cc * 32 + (lane >> 4) * 8 + j;
    float v = (ci < CIN) ? w[(co * CIN + ci) * TAPS + tap] : 0.f;
    wf[idx] = __float2bfloat16(v);
}

// ---------- cast features: tiled LDS transpose (b,80,t) fp32 -> XF (b,TPX,96) bf16 ----------
__global__ __launch_bounds__(256) void cast_feat_kernel(const float* __restrict__ f,
                                                        __hip_bfloat16* __restrict__ xf) {
    __shared__ unsigned short lds[64 * 100];
    const int tid = threadIdx.x;
    const int t0 = blockIdx.x * 64;
    const int b = blockIdx.y;

#pragma unroll
    for (int k = 0; k < 6; k++) {
        int idx = tid + k * 256;
        int f4 = idx & 15;
        int c = idx >> 4;
        float4 v = make_float4(0.f, 0.f, 0.f, 0.f);
        if (c < NMELS)
            v = *(const float4*)(f + ((size_t)b * NMELS + c) * T_LEN + t0 + f4 * 4);
        lds[(f4 * 4 + 0) * 100 + c] = f2bf(v.x);
        lds[(f4 * 4 + 1) * 100 + c] = f2bf(v.y);
        lds[(f4 * 4 + 2) * 100 + c] = f2bf(v.z);
        lds[(f4 * 4 + 3) * 100 + c] = f2bf(v.w);
    }
    __syncthreads();
    unsigned short* xp = (unsigned short*)xf;
#pragma unroll
    for (int k = 0; k < 6; k++) {
        int idx = tid + k * 256;
        int tl = idx / 24;
        int cq = idx - tl * 24;
        ushort4 o;
        o.x = lds[tl * 100 + cq * 4 + 0];
        o.y = lds[tl * 100 + cq * 4 + 1];
        o.z = lds[tl * 100 + cq * 4 + 2];
        o.w = lds[tl * 100 + cq * 4 + 3];
        *(ushort4*)(xp + ((size_t)b * TPX + t0 + tl + 10) * 96 + cq * 4) = o;
    }
}

// ---------- zero the 24 halo t-rows of XF (rows 0..9 and 4106..4119) ----------
__global__ void zero_xf_halo_kernel(__hip_bfloat16* __restrict__ p) {
    int r = blockIdx.x;            // 0..23
    int b = blockIdx.y;
    int row = (r < 10) ? r : 4096 + r; // 0..9, 4106..4119
    ((unsigned short*)p)[((size_t)b * TPX + row) * 96 + threadIdx.x] = 0;
}

// ---------- zero halo strips of P5 (b,68,120,128) ----------
__global__ __launch_bounds__(256) void zero_p5_halo_kernel(__hip_bfloat16* __restrict__ p) {
    int idx = blockIdx.x * 256 + threadIdx.x; // 32*1760*64
    if (idx >= 32 * 1760 * 64) return;
    int c2 = (idx & 63) * 2;
    int cell = idx >> 6;
    int b = cell / 1760;
    int cl = cell - b * 1760;
    int row, col;
    if (cl < 480) {
        int rr = cl / 120;
        row = (rr < 2) ? rr : 64 + rr;
        col = cl - rr * 120;
    } else {
        int cl2 = cl - 480;
        row = 2 + cl2 / 20;
        int q = cl2 % 20;
        col = (q < 2) ? q : 100 + q;
    }
    *(unsigned int*)((unsigned short*)p + (((size_t)b * WHALO + row) * DHALO + col) * 128 + c2) = 0u;
}

// ---------- FUSED conv1d x3: XF -> (h1,h2 in LDS) -> emb ----------
// Block = 64 out px, 256 thr = 4 waves; wave = 80px(5 frags) x 32co(2 mi).
// LDS: region A (1344 cells): XF [jg12][col84] (1008 used) then reused as h2 [jg16][84];
//      region H1 (1344 cells): h1 [jg16][84]. Col c <-> pixel pix0+c-10.
// CRITICAL: reference zero-pads EACH layer's input; h1/h2 stores are zeroed for
// out-of-sequence pixels (px<0 or px>=T_LEN) — real data leaks through edge taps otherwise.
__global__ __launch_bounds__(256, 3) void conv1d_fused_kernel(
    const __hip_bfloat16* __restrict__ xf, const __hip_bfloat16* __restrict__ wf1,
    const float* __restrict__ b1, const __hip_bfloat16* __restrict__ wf2,
    const float* __restrict__ b2, const __hip_bfloat16* __restrict__ wf3,
    const float* __restrict__ b3, __hip_bfloat16* __restrict__ emb) {
    __shared__ short lds[(1344 + 1344) * 8];
    short* A = lds;              // XF, then h2
    short* H1 = lds + 1344 * 8;  // h1
    const int tid = threadIdx.x;
    const int lane = tid & 63;
    const int wid = tid >> 6;    // co-quarter (32 co)
    const int pix0 = blockIdx.x * 64;
    const int b = blockIdx.y;

    // ---- stage XF: 1008 cells + 16 pad, 16 exact wave-transfers ----
    const short* xfp = (const short*)xf;
#pragma unroll
    for (int it = 0; it < 4; it++) {
        int cbase = (it * 4 + wid) * 64;
        if (cbase < 1008) {
            int cell = cbase + lane;
            int jg = cell / 84;
            int col = cell - jg * 84;
            if (jg > 11) { jg = 11; col = 83; } // pad lanes: clamp SOURCE (dest = pad cell)
            const short* g = xfp + ((size_t)(b * TPX + pix0 + col)) * 96 + jg * 8;
            gload16(g, A + (size_t)cbase * 8);
        }
    }
    __syncthreads(); // drain DMA

    const short* w1p = (const short*)wf1;
    const short* w2p = (const short*)wf2;
    const short* w3p = (const short*)wf3;

    f32x4 acc[5][2];

    // ---- layer 1: XF(A) -> h1(H1), relu ----
#pragma unroll
    for (int n = 0; n < 5; n++)
#pragma unroll
        for (int mi = 0; mi < 2; mi++) acc[n][mi] = (f32x4)0.f;
#pragma unroll 1
    for (int cc = 0; cc < 3; cc++) {
#pragma unroll
        for (int th = 0; th < 5; th++) {
            const short* wptr = w1p + ((cc * 5 + th) * 8 + wid * 2) * 512 + lane * 8;
            short8 wfr0 = *(const short8*)wptr;
            short8 wfr1 = *(const short8*)(wptr + 512);
            short8 xfr[5];
#pragma unroll
            for (int n = 0; n < 5; n++)
                xfr[n] = *(const short8*)&A[((cc * 4 + (lane >> 4)) * 84 +
                                             (n * 16 + (lane & 15) + th)) * 8];
#pragma unroll
            for (int n = 0; n < 5; n++) {
                acc[n][0] = __builtin_amdgcn_mfma_f32_16x16x32_bf16(wfr0, xfr[n], acc[n][0], 0, 0, 0);
                acc[n][1] = __builtin_amdgcn_mfma_f32_16x16x32_bf16(wfr1, xfr[n], acc[n][1], 0, 0, 0);
            }
        }
    }
#pragma unroll
    for (int mi = 0; mi < 2; mi++) {
        const float4 bv = *(const float4*)(b1 + wid * 32 + mi * 16 + (lane >> 4) * 4);
        const int jgI = wid * 4 + mi * 2 + ((lane >> 4) >> 1);
#pragma unroll
        for (int n = 0; n < 5; n++) {
            f32x4 a = acc[n][mi];
            const int col = n * 16 + (lane & 15) + 2;
            const int px = pix0 + col - 10;
            const bool inseq = ((unsigned)px < (unsigned)T_LEN);
            ushort4 o;
            o.x = inseq ? f2bf(fmaxf(a[0] + bv.x, 0.f)) : (unsigned short)0;
            o.y = inseq ? f2bf(fmaxf(a[1] + bv.y, 0.f)) : (unsigned short)0;
            o.z = inseq ? f2bf(fmaxf(a[2] + bv.z, 0.f)) : (unsigned short)0;
            o.w = inseq ? f2bf(fmaxf(a[3] + bv.w, 0.f)) : (unsigned short)0;
            *(ushort4*)&H1[(jgI * 84 + col) * 8 + ((lane >> 4) & 1) * 4] = o;
        }
    }
    __syncthreads(); // h1 published; XF reads done (A reusable)

    // ---- layer 2: h1(H1) -> h2(A), relu ----
#pragma unroll
    for (int n = 0; n < 5; n++)
#pragma unroll
        for (int mi = 0; mi < 2; mi++) acc[n][mi] = (f32x4)0.f;
#pragma unroll 1
    for (int cc = 0; cc < 4; cc++) {
#pragma unroll
        for (int th = 0; th < 5; th++) {
            const short* wptr = w2p + ((cc * 5 + th) * 8 + wid * 2) * 512 + lane * 8;
            short8 wfr0 = *(const short8*)wptr;
            short8 wfr1 = *(const short8*)(wptr + 512);
            short8 xfr[5];
#pragma unroll
            for (int n = 0; n < 5; n++)
                xfr[n] = *(const short8*)&H1[((cc * 4 + (lane >> 4)) * 84 +
                                              (n * 16 + (lane & 15) + th)) * 8];
#pragma unroll
            for (int n = 0; n < 5; n++) {
                acc[n][0] = __builtin_amdgcn_mfma_f32_16x16x32_bf16(wfr0, xfr[n], acc[n][0], 0, 0, 0);
                acc[n][1] = __builtin_amdgcn_mfma_f32_16x16x32_bf16(wfr1, xfr[n], acc[n][1], 0, 0, 0);
            }
        }
    }
#pragma unroll
    for (int mi = 0; mi < 2; mi++) {
        const float4 bv = *(const float4*)(b2 + wid * 32 + mi * 16 + (lane >> 4) * 4);
        const int jgI = wid * 4 + mi * 2 + ((lane >> 4) >> 1);
#pragma unroll
        for (int n = 0; n < 5; n++) {
            f32x4 a = acc[n][mi];
            const int col = n * 16 + (lane & 15) + 2;
            const int px = pix0 + col - 10;
            const bool inseq = ((unsigned)px < (unsigned)T_LEN);
            ushort4 o;
            o.x = inseq ? f2bf(fmaxf(a[0] + bv.x, 0.f)) : (unsigned short)0;
            o.y = inseq ? f2bf(fmaxf(a[1] + bv.y, 0.f)) : (unsigned short)0;
            o.z = inseq ? f2bf(fmaxf(a[2] + bv.z, 0.f)) : (unsigned short)0;
            o.w = inseq ? f2bf(fmaxf(a[3] + bv.w, 0.f)) : (unsigned short)0;
            *(ushort4*)&A[(jgI * 84 + col) * 8 + ((lane >> 4) & 1) * 4] = o;
        }
    }
    __syncthreads(); // h2 published

    // ---- layer 3: h2(A) -> emb global (no relu), 4 frags (64 px exact) ----
#pragma unroll
    for (int n = 0; n < 4; n++)
#pragma unroll
        for (int mi = 0; mi < 2; mi++) acc[n][mi] = (f32x4)0.f;
#pragma unroll 1
    for (int cc = 0; cc < 4; cc++) {
#pragma unroll
        for (int th = 0; th < 5; th++) {
            const short* wptr = w3p + ((cc * 5 + th) * 8 + wid * 2) * 512 + lane * 8;
            short8 wfr0 = *(const short8*)wptr;
            short8 wfr1 = *(const short8*)(wptr + 512);
            short8 xfr[4];
#pragma unroll
            for (int n = 0; n < 4; n++)
                xfr[n] = *(const short8*)&A[((cc * 4 + (lane >> 4)) * 84 +
                                             (n * 16 + (lane & 15) + th + 8)) * 8];
#pragma unroll
            for (int n = 0; n < 4; n++) {
                acc[n][0] = __builtin_amdgcn_mfma_f32_16x16x32_bf16(wfr0, xfr[n], acc[n][0], 0, 0, 0);
                acc[n][1] = __builtin_amdgcn_mfma_f32_16x16x32_bf16(wfr1, xfr[n], acc[n][1], 0, 0, 0);
            }
        }
    }
    unsigned short* ep = (unsigned short*)emb;
#pragma unroll
    for (int mi = 0; mi < 2; mi++) {
        const float4 bv = *(const float4*)(b3 + wid * 32 + mi * 16 + (lane >> 4) * 4);
#pragma unroll
        for (int n = 0; n < 4; n++) {
            f32x4 a = acc[n][mi];
            ushort4 o;
            o.x = f2bf(a[0] + bv.x);
            o.y = f2bf(a[1] + bv.y);
            o.z = f2bf(a[2] + bv.z);
            o.w = f2bf(a[3] + bv.w);
            const int px = pix0 + n * 16 + (lane & 15);
            *(ushort4*)(ep + ((size_t)(b * TP + px + 2)) * 128 + wid * 32 + mi * 16 +
                        (lane >> 4) * 4) = o;
        }
    }
}

// ---------- conv2d MFMA, gload_lds-staged single-buffer (round-13 form, unchanged) ----------
template <bool GATHER, bool RELU, int OMODE>
__global__ __launch_bounds__(512, 4) void conv2d_lds_kernel(const __hip_bfloat16* __restrict__ in,
                                                            const int* __restrict__ wb,
                                                            const __hip_bfloat16* __restrict__ wf,
                                                            const float* __restrict__ bias,
                                                            const __hip_bfloat16* __restrict__ zp,
                                                            const float* __restrict__ lw,
                                                            float* __restrict__ xep,
                                                            __hip_bfloat16* __restrict__ outp) {
    __shared__ short lds[4 * 8 * 68 * 8]; // 34,816 B; 2176 cells = 34*64 exact
    __shared__ int2 s_sd[8];
    const int tid = threadIdx.x;
    const int lane = tid & 63;
    const int wid = tid >> 6;
    const int wrow = wid & 3;
    const int cohalf = wid >> 2;
    const int w0 = (blockIdx.x & 15) * 4;
    const int dtile = blockIdx.x >> 4;
    const int D0 = dtile * 64;
    const int ntlim = dtile ? 3 : 4;
    const int b = blockIdx.y;
    const int w = w0 + wrow;

    if (GATHER && tid < 8) {
        int wg = w0 + tid - 2;
        int s = 0, du = 0;
        if (wg >= 0 && wg < 64) {
            s = wb[(b * 64 + wg) * 2];
            du = wb[(b * 64 + wg) * 2 + 1] - s;
            if (du > D_MAX) du = D_MAX;
        }
        s_sd[tid] = make_int2(s, du);
    }
    __syncthreads();

    const short* inp = (const short*)in;
    const short* wfp = (const short*)wf;

    auto stage = [&](int cc) {
#pragma unroll
        for (int it = 0; it < 5; it++) {
            int cbase = (it * 8 + wid) * 64;
            if (cbase < 2176) {
                int cell = cbase + lane;
                int jg = cell / 544;
                int rem = cell - jg * 544;
                int row = rem / 68;
                int col = rem - row * 68;
                const short* g;
                if (GATHER) {
                    int d = D0 + col - 2;
                    int2 sd = s_sd[row];
                    if ((unsigned)d < (unsigned)sd.y)
                        g = inp + ((size_t)(b * TP + 2 + sd.x + d)) * 128 + cc * 32 + jg * 8;
                    else
                        g = (const short*)zp;
                } else {
                    g = inp + ((size_t)((b * WHALO + w0 + row) * DHALO + D0 + col)) * 128 +
                        cc * 32 + jg * 8;
                }
                gload16(g, &lds[0] + (size_t)cbase * 8);
            }
        }
    };

    f32x4 acc[4][4];
#pragma unroll
    for (int n = 0; n < 4; n++)
#pragma unroll
        for (int mi = 0; mi < 4; mi++) acc[n][mi] = (f32x4)0.f;

#pragma unroll 1
    for (int cc = 0; cc < 4; cc++) {
        if (cc) __syncthreads();
        stage(cc);
        __syncthreads();
#pragma unroll 1
        for (int th = 0; th < 5; th++) {
#pragma unroll
            for (int tw = 0; tw < 5; tw++) {
                const int tap = th * 5 + tw;
                const short* wptr = wfp + ((cc * 25 + tap) * 8 + cohalf * 4) * 512 + lane * 8;
                short8 wfr[4];
#pragma unroll
                for (int mi = 0; mi < 4; mi++) wfr[mi] = *(const short8*)(wptr + mi * 512);

                short8 xfr[4];
#pragma unroll
                for (int n = 0; n < 4; n++)
                    if (n < ntlim)
                        xfr[n] = *(const short8*)&lds[(((lane >> 4) * 8 + wrow + th) * 68 +
                                                       (tw + n * 16 + (lane & 15))) * 8];

#pragma unroll
                for (int n = 0; n < 4; n++)
                    if (n < ntlim)
#pragma unroll
                        for (int mi = 0; mi < 4; mi++)
                            acc[n][mi] = __builtin_amdgcn_mfma_f32_16x16x32_bf16(
                                wfr[mi], xfr[n], acc[n][mi], 0, 0, 0);
            }
        }
    }

    if (OMODE == 1) {
        const int out_base = ((b * WHALO + w + 2) * DHALO + D0 + 2) * 128;
        unsigned short* outp16 = (unsigned short*)outp;
#pragma unroll
        for (int mi = 0; mi < 4; mi++) {
            const float4 bv = *(const float4*)(bias + cohalf * 64 + mi * 16 + (lane >> 4) * 4);
#pragma unroll
            for (int n = 0; n < 4; n++) {
                const int pix = n * 16 + (lane & 15);
                if (D0 + pix >= 100) continue;
                f32x4 a = acc[n][mi];
                float v0 = a[0] + bv.x, v1 = a[1] + bv.y, v2 = a[2] + bv.z, v3 = a[3] + bv.w;
                if (RELU) {
                    v0 = fmaxf(v0, 0.f); v1 = fmaxf(v1, 0.f);
                    v2 = fmaxf(v2, 0.f); v3 = fmaxf(v3, 0.f);
                }
                ushort4 o;
                o.x = f2bf(v0); o.y = f2bf(v1); o.z = f2bf(v2); o.w = f2bf(v3);
                *(ushort4*)(outp16 + out_base + pix * 128 + cohalf * 64 + mi * 16 +
                            (lane >> 4) * 4) = o;
            }
        }
    } else {
        float e[4][4];
#pragma unroll
        for (int mi = 0; mi < 4; mi++)
#pragma unroll
            for (int j = 0; j < 4; j++) e[mi][j] = 0.f;

#pragma unroll
        for (int mi = 0; mi < 4; mi++) {
            const float4 bv = *(const float4*)(bias + cohalf * 64 + mi * 16 + (lane >> 4) * 4);
#pragma unroll
            for (int n = 0; n < 4; n++) {
                const int pix = n * 16 + (lane & 15);
                if (D0 + pix >= 100) continue;
                const float lwv = lw[D0 + pix];
                f32x4 a = acc[n][mi];
                e[mi][0] += fmaxf(a[0] + bv.x, 0.f) * lwv;
                e[mi][1] += fmaxf(a[1] + bv.y, 0.f) * lwv;
                e[mi][2] += fmaxf(a[2] + bv.z, 0.f) * lwv;
                e[mi][3] += fmaxf(a[3] + bv.w, 0.f) * lwv;
            }
        }
#pragma unroll
        for (int mi = 0; mi < 4; mi++)
#pragma unroll
            for (int j = 0; j < 4; j++) {
                float v = e[mi][j];
                v += __shfl_xor(v, 1);
                v += __shfl_xor(v, 2);
                v += __shfl_xor(v, 4);
                v += __shfl_xor(v, 8);
                e[mi][j] = v;
            }
        if ((lane & 15) == 0) {
#pragma unroll
            for (int mi = 0; mi < 4; mi++)
#pragma unroll
                for (int j = 0; j < 4; j++) {
                    int co = cohalf * 64 + mi * 16 + (lane >> 4) * 4 + j;
                    xep[(((size_t)b * 128 + co) * 64 + w) * 2 + dtile] = e[mi][j];
                }
        }
    }
}

// ---------- final conv: XEp partials (b,128,64,2) + lb -> relu -> conv over w -> out ----------
__global__ void conv6_kernel(const float* __restrict__ xep, const float* __restrict__ lb,
                             const float* __restrict__ w6, const float* __restrict__ b6,
                             float* __restrict__ out) {
    int b = blockIdx.x;
    int w = threadIdx.x;
    float acc = b6[0];
    const float lb0 = lb[0];
#pragma unroll 1
    for (int ci = 0; ci < 128; ci++) {
        const float* xr = xep + (((size_t)b * 128 + ci) * 64) * 2;
#pragma unroll
        for (int kh = 0; kh < 5; kh++) {
            int ww = w + kh - 2;
            if ((unsigned)ww < 64u) {
                float x = fmaxf(xr[ww * 2] + xr[ww * 2 + 1] + lb0, 0.f);
                acc += x * w6[ci * 25 + kh * 5 + 2];
            }
        }
    }
    out[b * 64 + w] = acc;
}

extern "C" void kernel_launch(void* const* d_in, const int* in_sizes, int n_in,
                              void* d_out, int out_size, void* d_ws, size_t ws_size,
                              hipStream_t stream) {
    const float* features = (const float*)d_in[0];
    const int* wbnd = (const int*)d_in[1];
    const float* w1 = (const float*)d_in[2];
    const float* b1 = (const float*)d_in[3];
    const float* w2 = (const float*)d_in[4];
    const float* b2 = (const float*)d_in[5];
    const float* w3 = (const float*)d_in[6];
    const float* b3 = (const float*)d_in[7];
    const float* w4 = (const float*)d_in[8];
    const float* b4 = (const float*)d_in[9];
    const float* w5 = (const float*)d_in[10];
    const float* b5 = (const float*)d_in[11];
    const float* lw = (const float*)d_in[12];
    const float* lb = (const float*)d_in[13];
    const float* w6 = (const float*)d_in[14];
    const float* b6 = (const float*)d_in[15];
    float* out = (float*)d_out;

    char* base = (char*)d_ws;
    size_t off = 0;
    auto alloc = [&](size_t bytes) -> char* {
        char* p = base + off;
        off += (bytes + 255) & ~(size_t)255;
        return p;
    };

    __hip_bfloat16* ZP = (__hip_bfloat16*)alloc(256);
    __hip_bfloat16* XF = (__hip_bfloat16*)alloc((size_t)BATCH * TPX * 96 * 2);
    __hip_bfloat16* Y1 = (__hip_bfloat16*)alloc((size_t)BATCH * TP * 128 * 2);
    __hip_bfloat16* P5 = (__hip_bfloat16*)alloc((size_t)BATCH * WHALO * DHALO * 128 * 2);
    float* XEp = (float*)alloc((size_t)BATCH * 128 * 64 * 2 * 4);
    __hip_bfloat16* WF1 = (__hip_bfloat16*)alloc((size_t)3 * 5 * 8 * 512 * 2);
    __hip_bfloat16* WF2 = (__hip_bfloat16*)alloc((size_t)4 * 5 * 8 * 512 * 2);
    __hip_bfloat16* WF3 = (__hip_bfloat16*)alloc((size_t)4 * 5 * 8 * 512 * 2);
    __hip_bfloat16* WF4 = (__hip_bfloat16*)alloc((size_t)4 * 25 * 8 * 512 * 2);
    __hip_bfloat16* WF5 = (__hip_bfloat16*)alloc((size_t)4 * 25 * 8 * 512 * 2);

    hipMemsetAsync(ZP, 0, 256, stream);

    zero_xf_halo_kernel<<<dim3(24, 32), 96, 0, stream>>>(XF);
    zero_p5_halo_kernel<<<14080, 256, 0, stream>>>(P5);

    pack_w_kernel<80, 3, 5><<<240, 256, 0, stream>>>(w1, WF1);
    pack_w_kernel<128, 4, 5><<<320, 256, 0, stream>>>(w2, WF2);
    pack_w_kernel<128, 4, 5><<<320, 256, 0, stream>>>(w3, WF3);
    pack_w_kernel<128, 4, 25><<<1600, 256, 0, stream>>>(w4, WF4);
    pack_w_kernel<128, 4, 25><<<1600, 256, 0, stream>>>(w5, WF5);

    cast_feat_kernel<<<dim3(64, 32), 256, 0, stream>>>(features, XF);

    // fused conv1d x3: XF -> emb (Y1)
    conv1d_fused_kernel<<<dim3(64, 32), 256, 0, stream>>>(XF, WF1, b1, WF2, b2, WF3, b3, Y1);

    // conv4: gather fused into DMA staging; emb -> P5 (halo plane)
    conv2d_lds_kernel<true, true, 1><<<dim3(32, 32), 512, 0, stream>>>(Y1, wbnd, WF4, b4, ZP,
                                                                       nullptr, nullptr, P5);

    // conv5 + fused einsum: P5 -> XEp fp32 partials
    conv2d_lds_kernel<false, true, 2><<<dim3(32, 32), 512, 0, stream>>>(P5, wbnd, WF5, b5, ZP,
                                                                        lw, XEp, nullptr);

    conv6_kernel<<<32, 64, 0, stream>>>(XEp, lb, w6, b6, out);
}

// Round 16
// 475.840 us; speedup vs baseline: 2.5933x; 1.0151x over previous
//
#include <hip/hip_runtime.h>
#include <hip/hip_bf16.h>
#include <cstdint>
#include <cstddef>

#define T_LEN 4096
#define TP 4104      // emb rows: pixel t at row t+2; rows 0,1 and 4098..4103 zero
#define TPX 4120     // XF rows: pixel t at row t+10; rows 0..9 and 4106..4119 zero
#define BATCH 32
#define NMELS 80
#define HID 128
#define W_WORDS 64
#define D_MAX 100
#define WHALO 68
#define DHALO 120

typedef __attribute__((ext_vector_type(4))) float f32x4;
typedef __attribute__((ext_vector_type(8))) short short8;

static __device__ __forceinline__ unsigned short f2bf(float f) {
    __hip_bfloat16 h = __float2bfloat16(f);
    return *reinterpret_cast<unsigned short*>(&h);
}

// async global->LDS DMA, 16B per lane; dest = wave-uniform base + lane*16
typedef const __attribute__((address_space(1))) unsigned int* as1_u32p;
typedef __attribute__((address_space(3))) unsigned int* as3_u32p;
static __device__ __forceinline__ void gload16(const void* g, void* l) {
    __builtin_amdgcn_global_load_lds((as1_u32p)(uintptr_t)g, (as3_u32p)(uintptr_t)l, 16, 0, 0);
}

// ---------- pack weights into MFMA A-fragment order ----------
template <int CIN, int CC, int TAPS>
__global__ __launch_bounds__(256) void pack_w_kernel(const float* __restrict__ w,
                                                     __hip_bfloat16* __restrict__ wf) {
    int idx = blockIdx.x * 256 + threadIdx.x;
    int r = idx;
    int j = r & 7; r >>= 3;
    int lane = r & 63; r >>= 6;
    int mi = r & 7; r >>= 3;
    int tap = r % TAPS;
    int cc = r / TAPS;
    if (cc >= CC) return;
    int co = mi * 16 + (lane & 15);
    int ci = cc * 32 + (lane >> 4) * 8 + j;
    float v = (ci < CIN) ? w[(co * CIN + ci) * TAPS + tap] : 0.f;
    wf[idx] = __float2bfloat16(v);
}

// ---------- cast features: tiled LDS transpose (b,80,t) fp32 -> XF (b,TPX,96) bf16 ----------
__global__ __launch_bounds__(256) void cast_feat_kernel(const float* __restrict__ f,
                                                        __hip_bfloat16* __restrict__ xf) {
    __shared__ unsigned short lds[64 * 100];
    const int tid = threadIdx.x;
    const int t0 = blockIdx.x * 64;
    const int b = blockIdx.y;

#pragma unroll
    for (int k = 0; k < 6; k++) {
        int idx = tid + k * 256;
        int f4 = idx & 15;
        int c = idx >> 4;
        float4 v = make_float4(0.f, 0.f, 0.f, 0.f);
        if (c < NMELS)
            v = *(const float4*)(f + ((size_t)b * NMELS + c) * T_LEN + t0 + f4 * 4);
        lds[(f4 * 4 + 0) * 100 + c] = f2bf(v.x);
        lds[(f4 * 4 + 1) * 100 + c] = f2bf(v.y);
        lds[(f4 * 4 + 2) * 100 + c] = f2bf(v.z);
        lds[(f4 * 4 + 3) * 100 + c] = f2bf(v.w);
    }
    __syncthreads();
    unsigned short* xp = (unsigned short*)xf;
#pragma unroll
    for (int k = 0; k < 6; k++) {
        int idx = tid + k * 256;
        int tl = idx / 24;
        int cq = idx - tl * 24;
        ushort4 o;
        o.x = lds[tl * 100 + cq * 4 + 0];
        o.y = lds[tl * 100 + cq * 4 + 1];
        o.z = lds[tl * 100 + cq * 4 + 2];
        o.w = lds[tl * 100 + cq * 4 + 3];
        *(ushort4*)(xp + ((size_t)b * TPX + t0 + tl + 10) * 96 + cq * 4) = o;
    }
}

// ---------- zero the 24 halo t-rows of XF (rows 0..9 and 4106..4119) ----------
__global__ void zero_xf_halo_kernel(__hip_bfloat16* __restrict__ p) {
    int r = blockIdx.x;            // 0..23
    int b = blockIdx.y;
    int row = (r < 10) ? r : 4096 + r; // 0..9, 4106..4119
    ((unsigned short*)p)[((size_t)b * TPX + row) * 96 + threadIdx.x] = 0;
}

// ---------- zero halo strips of P5 (b,68,120,128) ----------
__global__ __launch_bounds__(256) void zero_p5_halo_kernel(__hip_bfloat16* __restrict__ p) {
    int idx = blockIdx.x * 256 + threadIdx.x; // 32*1760*64
    if (idx >= 32 * 1760 * 64) return;
    int c2 = (idx & 63) * 2;
    int cell = idx >> 6;
    int b = cell / 1760;
    int cl = cell - b * 1760;
    int row, col;
    if (cl < 480) {
        int rr = cl / 120;
        row = (rr < 2) ? rr : 64 + rr;
        col = cl - rr * 120;
    } else {
        int cl2 = cl - 480;
        row = 2 + cl2 / 20;
        int q = cl2 % 20;
        col = (q < 2) ? q : 100 + q;
    }
    *(unsigned int*)((unsigned short*)p + (((size_t)b * WHALO + row) * DHALO + col) * 128 + c2) = 0u;
}

// ---------- FUSED conv1d x3: XF -> (h1,h2 in LDS) -> emb (round-15 form, kept) ----------
__global__ __launch_bounds__(256, 3) void conv1d_fused_kernel(
    const __hip_bfloat16* __restrict__ xf, const __hip_bfloat16* __restrict__ wf1,
    const float* __restrict__ b1, const __hip_bfloat16* __restrict__ wf2,
    const float* __restrict__ b2, const __hip_bfloat16* __restrict__ wf3,
    const float* __restrict__ b3, __hip_bfloat16* __restrict__ emb) {
    __shared__ short lds[(1344 + 1344) * 8];
    short* A = lds;              // XF, then h2
    short* H1 = lds + 1344 * 8;  // h1
    const int tid = threadIdx.x;
    const int lane = tid & 63;
    const int wid = tid >> 6;    // co-quarter (32 co)
    const int pix0 = blockIdx.x * 64;
    const int b = blockIdx.y;

    const short* xfp = (const short*)xf;
#pragma unroll
    for (int it = 0; it < 4; it++) {
        int cbase = (it * 4 + wid) * 64;
        if (cbase < 1008) {
            int cell = cbase + lane;
            int jg = cell / 84;
            int col = cell - jg * 84;
            if (jg > 11) { jg = 11; col = 83; } // pad lanes: clamp SOURCE (dest = pad cell)
            const short* g = xfp + ((size_t)(b * TPX + pix0 + col)) * 96 + jg * 8;
            gload16(g, A + (size_t)cbase * 8);
        }
    }
    __syncthreads(); // drain DMA

    const short* w1p = (const short*)wf1;
    const short* w2p = (const short*)wf2;
    const short* w3p = (const short*)wf3;

    f32x4 acc[5][2];

    // ---- layer 1: XF(A) -> h1(H1), relu ----
#pragma unroll
    for (int n = 0; n < 5; n++)
#pragma unroll
        for (int mi = 0; mi < 2; mi++) acc[n][mi] = (f32x4)0.f;
#pragma unroll 1
    for (int cc = 0; cc < 3; cc++) {
#pragma unroll
        for (int th = 0; th < 5; th++) {
            const short* wptr = w1p + ((cc * 5 + th) * 8 + wid * 2) * 512 + lane * 8;
            short8 wfr0 = *(const short8*)wptr;
            short8 wfr1 = *(const short8*)(wptr + 512);
            short8 xfr[5];
#pragma unroll
            for (int n = 0; n < 5; n++)
                xfr[n] = *(const short8*)&A[((cc * 4 + (lane >> 4)) * 84 +
                                             (n * 16 + (lane & 15) + th)) * 8];
#pragma unroll
            for (int n = 0; n < 5; n++) {
                acc[n][0] = __builtin_amdgcn_mfma_f32_16x16x32_bf16(wfr0, xfr[n], acc[n][0], 0, 0, 0);
                acc[n][1] = __builtin_amdgcn_mfma_f32_16x16x32_bf16(wfr1, xfr[n], acc[n][1], 0, 0, 0);
            }
        }
    }
#pragma unroll
    for (int mi = 0; mi < 2; mi++) {
        const float4 bv = *(const float4*)(b1 + wid * 32 + mi * 16 + (lane >> 4) * 4);
        const int jgI = wid * 4 + mi * 2 + ((lane >> 4) >> 1);
#pragma unroll
        for (int n = 0; n < 5; n++) {
            f32x4 a = acc[n][mi];
            const int col = n * 16 + (lane & 15) + 2;
            const int px = pix0 + col - 10;
            const bool inseq = ((unsigned)px < (unsigned)T_LEN);
            ushort4 o;
            o.x = inseq ? f2bf(fmaxf(a[0] + bv.x, 0.f)) : (unsigned short)0;
            o.y = inseq ? f2bf(fmaxf(a[1] + bv.y, 0.f)) : (unsigned short)0;
            o.z = inseq ? f2bf(fmaxf(a[2] + bv.z, 0.f)) : (unsigned short)0;
            o.w = inseq ? f2bf(fmaxf(a[3] + bv.w, 0.f)) : (unsigned short)0;
            *(ushort4*)&H1[(jgI * 84 + col) * 8 + ((lane >> 4) & 1) * 4] = o;
        }
    }
    __syncthreads(); // h1 published; XF reads done (A reusable)

    // ---- layer 2: h1(H1) -> h2(A), relu ----
#pragma unroll
    for (int n = 0; n < 5; n++)
#pragma unroll
        for (int mi = 0; mi < 2; mi++) acc[n][mi] = (f32x4)0.f;
#pragma unroll 1
    for (int cc = 0; cc < 4; cc++) {
#pragma unroll
        for (int th = 0; th < 5; th++) {
            const short* wptr = w2p + ((cc * 5 + th) * 8 + wid * 2) * 512 + lane * 8;
            short8 wfr0 = *(const short8*)wptr;
            short8 wfr1 = *(const short8*)(wptr + 512);
            short8 xfr[5];
#pragma unroll
            for (int n = 0; n < 5; n++)
                xfr[n] = *(const short8*)&H1[((cc * 4 + (lane >> 4)) * 84 +
                                              (n * 16 + (lane & 15) + th)) * 8];
#pragma unroll
            for (int n = 0; n < 5; n++) {
                acc[n][0] = __builtin_amdgcn_mfma_f32_16x16x32_bf16(wfr0, xfr[n], acc[n][0], 0, 0, 0);
                acc[n][1] = __builtin_amdgcn_mfma_f32_16x16x32_bf16(wfr1, xfr[n], acc[n][1], 0, 0, 0);
            }
        }
    }
#pragma unroll
    for (int mi = 0; mi < 2; mi++) {
        const float4 bv = *(const float4*)(b2 + wid * 32 + mi * 16 + (lane >> 4) * 4);
        const int jgI = wid * 4 + mi * 2 + ((lane >> 4) >> 1);
#pragma unroll
        for (int n = 0; n < 5; n++) {
            f32x4 a = acc[n][mi];
            const int col = n * 16 + (lane & 15) + 2;
            const int px = pix0 + col - 10;
            const bool inseq = ((unsigned)px < (unsigned)T_LEN);
            ushort4 o;
            o.x = inseq ? f2bf(fmaxf(a[0] + bv.x, 0.f)) : (unsigned short)0;
            o.y = inseq ? f2bf(fmaxf(a[1] + bv.y, 0.f)) : (unsigned short)0;
            o.z = inseq ? f2bf(fmaxf(a[2] + bv.z, 0.f)) : (unsigned short)0;
            o.w = inseq ? f2bf(fmaxf(a[3] + bv.w, 0.f)) : (unsigned short)0;
            *(ushort4*)&A[(jgI * 84 + col) * 8 + ((lane >> 4) & 1) * 4] = o;
        }
    }
    __syncthreads(); // h2 published

    // ---- layer 3: h2(A) -> emb global (no relu), 4 frags (64 px exact) ----
#pragma unroll
    for (int n = 0; n < 4; n++)
#pragma unroll
        for (int mi = 0; mi < 2; mi++) acc[n][mi] = (f32x4)0.f;
#pragma unroll 1
    for (int cc = 0; cc < 4; cc++) {
#pragma unroll
        for (int th = 0; th < 5; th++) {
            const short* wptr = w3p + ((cc * 5 + th) * 8 + wid * 2) * 512 + lane * 8;
            short8 wfr0 = *(const short8*)wptr;
            short8 wfr1 = *(const short8*)(wptr + 512);
            short8 xfr[4];
#pragma unroll
            for (int n = 0; n < 4; n++)
                xfr[n] = *(const short8*)&A[((cc * 4 + (lane >> 4)) * 84 +
                                             (n * 16 + (lane & 15) + th + 8)) * 8];
#pragma unroll
            for (int n = 0; n < 4; n++) {
                acc[n][0] = __builtin_amdgcn_mfma_f32_16x16x32_bf16(wfr0, xfr[n], acc[n][0], 0, 0, 0);
                acc[n][1] = __builtin_amdgcn_mfma_f32_16x16x32_bf16(wfr1, xfr[n], acc[n][1], 0, 0, 0);
            }
        }
    }
    unsigned short* ep = (unsigned short*)emb;
#pragma unroll
    for (int mi = 0; mi < 2; mi++) {
        const float4 bv = *(const float4*)(b3 + wid * 32 + mi * 16 + (lane >> 4) * 4);
#pragma unroll
        for (int n = 0; n < 4; n++) {
            f32x4 a = acc[n][mi];
            ushort4 o;
            o.x = f2bf(a[0] + bv.x);
            o.y = f2bf(a[1] + bv.y);
            o.z = f2bf(a[2] + bv.z);
            o.w = f2bf(a[3] + bv.w);
            const int px = pix0 + n * 16 + (lane & 15);
            *(ushort4*)(ep + ((size_t)(b * TP + px + 2)) * 128 + wid * 32 + mi * 16 +
                        (lane >> 4) * 4) = o;
        }
    }
}

// ---------- conv2d MFMA, 64-ci slab staging (half the barriers), 512-thr block ----------
// LDS [jg(8)][row(8)][col(NCst)] 16B cells; NCst = 68 (dtile0) / 52 (dtile1); both
// whole-wave-exact (4352 / 3328 cells). 69.6 KB -> 2 blocks/CU; occupancy is reg-capped
// at 16 waves/CU anyway, so the big slab costs nothing and halves barrier count.
// 25-tap loop fully unrolled so weight loads (L2-resident) pipeline across taps.
template <bool GATHER, bool RELU, int OMODE>
__global__ __launch_bounds__(512, 4) void conv2d_lds_kernel(const __hip_bfloat16* __restrict__ in,
                                                            const int* __restrict__ wb,
                                                            const __hip_bfloat16* __restrict__ wf,
                                                            const float* __restrict__ bias,
                                                            const __hip_bfloat16* __restrict__ zp,
                                                            const float* __restrict__ lw,
                                                            float* __restrict__ xep,
                                                            __hip_bfloat16* __restrict__ outp) {
    __shared__ short lds[8 * 8 * 68 * 8]; // 69,632 B max
    __shared__ int2 s_sd[8];
    const int tid = threadIdx.x;
    const int lane = tid & 63;
    const int wid = tid >> 6;
    const int wrow = wid & 3;
    const int cohalf = wid >> 2;
    const int w0 = (blockIdx.x & 15) * 4;
    const int dtile = blockIdx.x >> 4;
    const int D0 = dtile * 64;
    const int ntlim = dtile ? 3 : 4;
    const int NCst = dtile ? 52 : 68;
    const int b = blockIdx.y;
    const int w = w0 + wrow;

    if (GATHER && tid < 8) {
        int wg = w0 + tid - 2;
        int s = 0, du = 0;
        if (wg >= 0 && wg < 64) {
            s = wb[(b * 64 + wg) * 2];
            du = wb[(b * 64 + wg) * 2 + 1] - s;
            if (du > D_MAX) du = D_MAX;
        }
        s_sd[tid] = make_int2(s, du);
    }
    __syncthreads(); // s_sd visible before staging

    const short* inp = (const short*)in;
    const short* wfp = (const short*)wf;

    // stage one 64-ci slab (ccp = 0 or 1); ci = ccp*64 + jg*8
    auto stage = [&](int ccp) {
        const int ncells = 8 * 8 * NCst; // 4352 or 3328, both = k*64
#pragma unroll
        for (int it = 0; it < 9; it++) {
            int cbase = (it * 8 + wid) * 64;
            if (cbase < ncells) {
                int cell = cbase + lane;
                int jg, rem;
                if (dtile == 0) { jg = cell / 544; rem = cell - jg * 544; }
                else            { jg = cell / 416; rem = cell - jg * 416; }
                int row, col;
                if (dtile == 0) { row = rem / 68; col = rem - row * 68; }
                else            { row = rem / 52; col = rem - row * 52; }
                const short* g;
                if (GATHER) {
                    int d = D0 + col - 2;
                    int2 sd = s_sd[row];
                    if ((unsigned)d < (unsigned)sd.y)
                        g = inp + ((size_t)(b * TP + 2 + sd.x + d)) * 128 + ccp * 64 + jg * 8;
                    else
                        g = (const short*)zp;
                } else {
                    g = inp + ((size_t)((b * WHALO + w0 + row) * DHALO + D0 + col)) * 128 +
                        ccp * 64 + jg * 8;
                }
                gload16(g, &lds[0] + (size_t)cbase * 8);
            }
        }
    };

    f32x4 acc[4][4];
#pragma unroll
    for (int n = 0; n < 4; n++)
#pragma unroll
        for (int mi = 0; mi < 4; mi++) acc[n][mi] = (f32x4)0.f;

#pragma unroll 1
    for (int ccp = 0; ccp < 2; ccp++) {
        if (ccp) __syncthreads(); // readers of lds done
        stage(ccp);               // async DMA issue
        __syncthreads();          // drain -> slab ready
#pragma unroll 1
        for (int cch = 0; cch < 2; cch++) {
            const int cc = ccp * 2 + cch;
#pragma unroll
            for (int th = 0; th < 5; th++) {
#pragma unroll
                for (int tw = 0; tw < 5; tw++) {
                    const int tap = th * 5 + tw;
                    const short* wptr =
                        wfp + ((cc * 25 + tap) * 8 + cohalf * 4) * 512 + lane * 8;
                    short8 wfr[4];
#pragma unroll
                    for (int mi = 0; mi < 4; mi++) wfr[mi] = *(const short8*)(wptr + mi * 512);

                    short8 xfr[4];
#pragma unroll
                    for (int n = 0; n < 4; n++)
                        if (n < ntlim)
                            xfr[n] = *(const short8*)&lds[(((cch * 4 + (lane >> 4)) * 8 + wrow +
                                                            th) * NCst +
                                                           (tw + n * 16 + (lane & 15))) * 8];

#pragma unroll
                    for (int n = 0; n < 4; n++)
                        if (n < ntlim)
#pragma unroll
                            for (int mi = 0; mi < 4; mi++)
                                acc[n][mi] = __builtin_amdgcn_mfma_f32_16x16x32_bf16(
                                    wfr[mi], xfr[n], acc[n][mi], 0, 0, 0);
                }
            }
        }
    }

    if (OMODE == 1) {
        const int out_base = ((b * WHALO + w + 2) * DHALO + D0 + 2) * 128;
        unsigned short* outp16 = (unsigned short*)outp;
#pragma unroll
        for (int mi = 0; mi < 4; mi++) {
            const float4 bv = *(const float4*)(bias + cohalf * 64 + mi * 16 + (lane >> 4) * 4);
#pragma unroll
            for (int n = 0; n < 4; n++) {
                const int pix = n * 16 + (lane & 15);
                if (D0 + pix >= 100) continue;
                f32x4 a = acc[n][mi];
                float v0 = a[0] + bv.x, v1 = a[1] + bv.y, v2 = a[2] + bv.z, v3 = a[3] + bv.w;
                if (RELU) {
                    v0 = fmaxf(v0, 0.f); v1 = fmaxf(v1, 0.f);
                    v2 = fmaxf(v2, 0.f); v3 = fmaxf(v3, 0.f);
                }
                ushort4 o;
                o.x = f2bf(v0); o.y = f2bf(v1); o.z = f2bf(v2); o.w = f2bf(v3);
                *(ushort4*)(outp16 + out_base + pix * 128 + cohalf * 64 + mi * 16 +
                            (lane >> 4) * 4) = o;
            }
        }
    } else {
        float e[4][4];
#pragma unroll
        for (int mi = 0; mi < 4; mi++)
#pragma unroll
            for (int j = 0; j < 4; j++) e[mi][j] = 0.f;

#pragma unroll
        for (int mi = 0; mi < 4; mi++) {
            const float4 bv = *(const float4*)(bias + cohalf * 64 + mi * 16 + (lane >> 4) * 4);
#pragma unroll
            for (int n = 0; n < 4; n++) {
                const int pix = n * 16 + (lane & 15);
                if (D0 + pix >= 100) continue;
                const float lwv = lw[D0 + pix];
                f32x4 a = acc[n][mi];
                e[mi][0] += fmaxf(a[0] + bv.x, 0.f) * lwv;
                e[mi][1] += fmaxf(a[1] + bv.y, 0.f) * lwv;
                e[mi][2] += fmaxf(a[2] + bv.z, 0.f) * lwv;
                e[mi][3] += fmaxf(a[3] + bv.w, 0.f) * lwv;
            }
        }
#pragma unroll
        for (int mi = 0; mi < 4; mi++)
#pragma unroll
            for (int j = 0; j < 4; j++) {
                float v = e[mi][j];
                v += __shfl_xor(v, 1);
                v += __shfl_xor(v, 2);
                v += __shfl_xor(v, 4);
                v += __shfl_xor(v, 8);
                e[mi][j] = v;
            }
        if ((lane & 15) == 0) {
#pragma unroll
            for (int mi = 0; mi < 4; mi++)
#pragma unroll
                for (int j = 0; j < 4; j++) {
                    int co = cohalf * 64 + mi * 16 + (lane >> 4) * 4 + j;
                    xep[(((size_t)b * 128 + co) * 64 + w) * 2 + dtile] = e[mi][j];
                }
        }
    }
}

// ---------- final conv: XEp partials (b,128,64,2) -> out (b,64); ci-parallel ----------
__global__ __launch_bounds__(256) void conv6_kernel(const float* __restrict__ xep,
                                                    const float* __restrict__ lb,
                                                    const float* __restrict__ w6,
                                                    const float* __restrict__ b6,
                                                    float* __restrict__ out) {
    __shared__ float red[256];
    const int b = blockIdx.x;
    const int w = threadIdx.x & 63;
    const int cq = threadIdx.x >> 6; // 4 groups of 32 ci
    const float lb0 = lb[0];
    float partial = 0.f;
#pragma unroll 1
    for (int ci = cq * 32; ci < cq * 32 + 32; ci++) {
        const float* xr = xep + (((size_t)b * 128 + ci) * 64) * 2;
#pragma unroll
        for (int kh = 0; kh < 5; kh++) {
            int ww = w + kh - 2;
            if ((unsigned)ww < 64u) {
                float x = fmaxf(xr[ww * 2] + xr[ww * 2 + 1] + lb0, 0.f);
                partial += x * w6[ci * 25 + kh * 5 + 2];
            }
        }
    }
    red[threadIdx.x] = partial;
    __syncthreads();
    if (cq == 0)
        out[b * 64 + w] = red[w] + red[w + 64] + red[w + 128] + red[w + 192] + b6[0];
}

extern "C" void kernel_launch(void* const* d_in, const int* in_sizes, int n_in,
                              void* d_out, int out_size, void* d_ws, size_t ws_size,
                              hipStream_t stream) {
    const float* features = (const float*)d_in[0];
    const int* wbnd = (const int*)d_in[1];
    const float* w1 = (const float*)d_in[2];
    const float* b1 = (const float*)d_in[3];
    const float* w2 = (const float*)d_in[4];
    const float* b2 = (const float*)d_in[5];
    const float* w3 = (const float*)d_in[6];
    const float* b3 = (const float*)d_in[7];
    const float* w4 = (const float*)d_in[8];
    const float* b4 = (const float*)d_in[9];
    const float* w5 = (const float*)d_in[10];
    const float* b5 = (const float*)d_in[11];
    const float* lw = (const float*)d_in[12];
    const float* lb = (const float*)d_in[13];
    const float* w6 = (const float*)d_in[14];
    const float* b6 = (const float*)d_in[15];
    float* out = (float*)d_out;

    char* base = (char*)d_ws;
    size_t off = 0;
    auto alloc = [&](size_t bytes) -> char* {
        char* p = base + off;
        off += (bytes + 255) & ~(size_t)255;
        return p;
    };

    __hip_bfloat16* ZP = (__hip_bfloat16*)alloc(256);
    __hip_bfloat16* XF = (__hip_bfloat16*)alloc((size_t)BATCH * TPX * 96 * 2);
    __hip_bfloat16* Y1 = (__hip_bfloat16*)alloc((size_t)BATCH * TP * 128 * 2);
    __hip_bfloat16* P5 = (__hip_bfloat16*)alloc((size_t)BATCH * WHALO * DHALO * 128 * 2);
    float* XEp = (float*)alloc((size_t)BATCH * 128 * 64 * 2 * 4);
    __hip_bfloat16* WF1 = (__hip_bfloat16*)alloc((size_t)3 * 5 * 8 * 512 * 2);
    __hip_bfloat16* WF2 = (__hip_bfloat16*)alloc((size_t)4 * 5 * 8 * 512 * 2);
    __hip_bfloat16* WF3 = (__hip_bfloat16*)alloc((size_t)4 * 5 * 8 * 512 * 2);
    __hip_bfloat16* WF4 = (__hip_bfloat16*)alloc((size_t)4 * 25 * 8 * 512 * 2);
    __hip_bfloat16* WF5 = (__hip_bfloat16*)alloc((size_t)4 * 25 * 8 * 512 * 2);

    hipMemsetAsync(ZP, 0, 256, stream);

    zero_xf_halo_kernel<<<dim3(24, 32), 96, 0, stream>>>(XF);
    zero_p5_halo_kernel<<<14080, 256, 0, stream>>>(P5);

    pack_w_kernel<80, 3, 5><<<240, 256, 0, stream>>>(w1, WF1);
    pack_w_kernel<128, 4, 5><<<320, 256, 0, stream>>>(w2, WF2);
    pack_w_kernel<128, 4, 5><<<320, 256, 0, stream>>>(w3, WF3);
    pack_w_kernel<128, 4, 25><<<1600, 256, 0, stream>>>(w4, WF4);
    pack_w_kernel<128, 4, 25><<<1600, 256, 0, stream>>>(w5, WF5);

    cast_feat_kernel<<<dim3(64, 32), 256, 0, stream>>>(features, XF);

    // fused conv1d x3: XF -> emb (Y1)
    conv1d_fused_kernel<<<dim3(64, 32), 256, 0, stream>>>(XF, WF1, b1, WF2, b2, WF3, b3, Y1);

    // conv4: gather fused into DMA staging; emb -> P5 (halo plane)
    conv2d_lds_kernel<true, true, 1><<<dim3(32, 32), 512, 0, stream>>>(Y1, wbnd, WF4, b4, ZP,
                                                                       nullptr, nullptr, P5);

    // conv5 + fused einsum: P5 -> XEp fp32 partials
    conv2d_lds_kernel<false, true, 2><<<dim3(32, 32), 512, 0, stream>>>(P5, wbnd, WF5, b5, ZP,
                                                                        lw, XEp, nullptr);

    conv6_kernel<<<32, 256, 0, stream>>>(XEp, lb, w6, b6, out);
}